// Round 9
// baseline (427.388 us; speedup 1.0000x reference)
//
#include <hip/hip_runtime.h>
#include <stdint.h>

typedef unsigned short u16;
typedef unsigned int   u32;

typedef __attribute__((ext_vector_type(8)))  short bf16x8;
typedef __attribute__((ext_vector_type(4)))  float f32x4;
typedef __attribute__((ext_vector_type(4)))  unsigned int u32x4;

// ---------- bf16 helpers (raw ushort representation) ----------
__device__ __forceinline__ float b2f(u16 u) { return __uint_as_float(((u32)u) << 16); }
__device__ __forceinline__ float blo(u32 u) { return __uint_as_float(u << 16); }
__device__ __forceinline__ float bhi(u32 u) { return __uint_as_float(u & 0xffff0000u); }
__device__ __forceinline__ u16 f2b(float f) {
    u32 x = __float_as_uint(f);
    u32 r = (x + 0x7fffu + ((x >> 16) & 1u)) >> 16;
    return (u16)r;
}

#define NB   4
#define IC   256
#define NPOS 4096
#define CH   64
#define HW   16384

// ======================================================================
// prep: transpose small weights (fp32) + cast QKV weights to bf16
// ======================================================================
__global__ __launch_bounds__(256) void prep_kernel(
    const float* __restrict__ wsw, const float* __restrict__ wcw,
    const float* __restrict__ m1w,
    const float* __restrict__ thw, const float* __restrict__ phw, const float* __restrict__ gw,
    float* __restrict__ wswT, float* __restrict__ wcwT, float* __restrict__ m1wT,
    u16* __restrict__ wbf)
{
    int idx = blockIdx.x * 256 + threadIdx.x;
    if (idx < 65536) {
        wbf[idx]          = f2b(thw[idx]);
        wbf[idx + 65536]  = f2b(phw[idx]);
        wbf[idx + 131072] = f2b(gw[idx]);
    }
    if (idx < 4096) {
        int i = idx >> 6, c = idx & 63;
        wswT[i*64 + c] = wsw[c*64 + i];   // [i][c]: per-i rows contiguous
        wcwT[i*64 + c] = wcw[c*64 + i];
    }
    if (idx < 9216) {
        int o = idx & 15, ct = idx >> 4;
        int t = ct % 9, c = ct / 9;
        m1wT[idx] = m1w[(o*64 + c)*9 + t]; // [(c,t)][o]: 16 contiguous per tap
    }
}

// ======================================================================
// QKV via MFMA. One block: one of {Q,K,V} x [256 o][64 n] tile, K=256.
// v2: float4-vectorized x staging (16 vec loads/thread vs 64 scalar).
// ======================================================================
__global__ __launch_bounds__(256) void qkv_mfma_kernel(
    const float* __restrict__ x, const u16* __restrict__ wbf,
    const float* __restrict__ thb, const float* __restrict__ phb, const float* __restrict__ gb,
    u16* __restrict__ Q, u16* __restrict__ K, u16* __restrict__ VT)
{
    __shared__ __align__(16) u32 xT[64*132];     // 33 KB, reused for epilogue transpose
    __shared__ __align__(16) float bias_l[256];
    const int tid  = threadIdx.x;
    const int w    = tid >> 6;
    const int lane = tid & 63;
    const int q4   = lane >> 4;
    const int l    = lane & 15;
    const int n0   = blockIdx.x * 64;
    const int b    = blockIdx.y;
    const int mat  = blockIdx.z;
    const u16* wmat = wbf + mat * 65536;
    const float* bias = (mat == 0) ? thb : (mat == 1) ? phb : gb;

    bias_l[tid] = bias[tid];

    // ---- stage x tile: u16 view xT16[n*264 + i] = bf16(x[b][i][n0+n]) ----
    {
        u16* xT16 = (u16*)xT;
        const int rq = tid >> 4;        // row-subgroup 0..15
        const int nq = tid & 15;        // n-quad 0..15
        const float* xb = x + ((size_t)b*IC)*NPOS + n0 + nq*4;
        #pragma unroll 4
        for (int p2=0; p2<16; p2++){
            int i = p2*16 + rq;         // channel row 0..255
            float4 v = *(const float4*)(xb + (size_t)i*NPOS);
            xT16[(nq*4+0)*264 + i] = f2b(v.x);
            xT16[(nq*4+1)*264 + i] = f2b(v.y);
            xT16[(nq*4+2)*264 + i] = f2b(v.z);
            xT16[(nq*4+3)*264 + i] = f2b(v.w);
        }
    }
    __syncthreads();

    f32x4 acc[4][4];
    #pragma unroll
    for (int ot=0; ot<4; ot++)
        #pragma unroll
        for (int nt=0; nt<4; nt++) acc[ot][nt] = (f32x4){0.f,0.f,0.f,0.f};

    // ---- K-loop: 8 steps of 32 ----
    #pragma unroll
    for (int f=0; f<8; f++){
        bf16x8 bfrag[4];
        #pragma unroll
        for (int nt=0; nt<4; nt++)
            bfrag[nt] = *(const bf16x8*)&xT[(nt*16 + l)*132 + f*16 + q4*4];
        #pragma unroll
        for (int ot=0; ot<4; ot++){
            bf16x8 afrag = *(const bf16x8*)(wmat + (size_t)(w*64 + ot*16 + l)*256 + f*32 + q4*8);
            #pragma unroll
            for (int nt=0; nt<4; nt++)
                acc[ot][nt] = __builtin_amdgcn_mfma_f32_16x16x32_bf16(afrag, bfrag[nt], acc[ot][nt], 0, 0, 0);
        }
    }
    __syncthreads();   // xT B-frag reads done; reuse buffer for transpose

    if (mat < 2){
        // ---- Q/K: transpose to [n][o] (stride 264 u16), coalesced store ----
        u16* zbuf = (u16*)xT;
        #pragma unroll
        for (int nt=0; nt<4; nt++)
            #pragma unroll
            for (int ot=0; ot<4; ot++){
                int o = w*64 + ot*16 + q4*4;
                float4 bv = *(const float4*)&bias_l[o];
                uint2 pk;
                pk.x = (u32)f2b(acc[ot][nt][0]+bv.x) | ((u32)f2b(acc[ot][nt][1]+bv.y) << 16);
                pk.y = (u32)f2b(acc[ot][nt][2]+bv.z) | ((u32)f2b(acc[ot][nt][3]+bv.w) << 16);
                *(uint2*)&zbuf[(nt*16 + l)*264 + o] = pk;
            }
        __syncthreads();
        u16* dst = ((mat == 0) ? Q : K) + ((size_t)(b*NPOS + n0))*IC;
        int n = tid >> 2, o0 = (tid & 3)*64;
        const u32* src = &xT[n*132 + (tid & 3)*32];
        #pragma unroll
        for (int m=0; m<8; m++)
            *(uint4*)(dst + (size_t)n*IC + o0 + m*8) = ((const uint4*)src)[m];
    } else {
        // ---- V: transpose to [o][n] (stride 66 u16), store VT rows ----
        u16* zbuf = (u16*)xT;
        #pragma unroll
        for (int nt=0; nt<4; nt++)
            #pragma unroll
            for (int ot=0; ot<4; ot++){
                int o = w*64 + ot*16 + q4*4;
                int n = nt*16 + l;
                #pragma unroll
                for (int reg=0; reg<4; reg++)
                    zbuf[(o+reg)*66 + n] = f2b(acc[ot][nt][reg] + bias_l[o+reg]);
            }
        __syncthreads();
        const u32* src = &xT[tid*33];
        u32 tmp[32];
        #pragma unroll
        for (int m=0; m<32; m++) tmp[m] = src[m];
        u16* dst = VT + ((size_t)(b*IC + tid))*NPOS + n0;
        #pragma unroll
        for (int m=0; m<8; m++){
            uint4 v; v.x = tmp[m*4]; v.y = tmp[m*4+1]; v.z = tmp[m*4+2]; v.w = tmp[m*4+3];
            *(uint4*)(dst + m*8) = v;
        }
    }
}

// ======================================================================
// fc via MFMA: fc[c][d] = sum_n Q[n][c]*K[n][d]. Split-n partials.
// v2: nsegs split-n (8 when workspace allows) for 2 blocks/CU.
// Grid (4,4,NB<<nslg); z = b<<nslg | ns.
// ======================================================================
__global__ __launch_bounds__(256) void fc_mfma_kernel(
    const u16* __restrict__ Q, const u16* __restrict__ K, float* __restrict__ fcp,
    int nslg)
{
    __shared__ __align__(16) u16 QT[64*72];   // 9 KB each, stride 72 (b128-aligned)
    __shared__ __align__(16) u16 KT[64*72];
    const int tid = threadIdx.x;
    const int w   = tid >> 6;
    const int lane = tid & 63;
    const int q4  = lane >> 4;
    const int l   = lane & 15;
    const int c0  = blockIdx.x * 64;
    const int d0  = blockIdx.y * 64;
    const int b   = blockIdx.z >> nslg;
    const int ns  = blockIdx.z & ((1 << nslg) - 1);
    const int chunks = 64 >> nslg;

    f32x4 acc[4];
    #pragma unroll
    for (int dt=0; dt<4; dt++) acc[dt] = (f32x4){0.f,0.f,0.f,0.f};

    for (int chunk=0; chunk<chunks; chunk++){
        const int n0 = (ns*chunks + chunk)*64;
        __syncthreads();
        {   // stage Q/K tiles transposed: [c|d][n], 16 cols per thread
            int r  = tid >> 2;            // n within chunk
            int cq = (tid & 3) * 16;
            const u16* qs = Q + ((size_t)(b*NPOS + n0 + r))*IC + c0 + cq;
            const u16* ks = K + ((size_t)(b*NPOS + n0 + r))*IC + d0 + cq;
            u16 qv[16], kv[16];
            *(uint4*)&qv[0] = *(const uint4*)qs;
            *(uint4*)&qv[8] = *(const uint4*)(qs + 8);
            *(uint4*)&kv[0] = *(const uint4*)ks;
            *(uint4*)&kv[8] = *(const uint4*)(ks + 8);
            #pragma unroll
            for (int j=0;j<16;j++){
                QT[(cq+j)*72 + r] = qv[j];
                KT[(cq+j)*72 + r] = kv[j];
            }
        }
        __syncthreads();
        // D[c][d] += sum_n A[c][n]*B[d][n]; 2 k-steps of 32
        #pragma unroll
        for (int f=0; f<2; f++){
            bf16x8 af = *(const bf16x8*)&QT[(w*16 + l)*72 + f*32 + q4*8];
            #pragma unroll
            for (int dt=0; dt<4; dt++){
                bf16x8 bf2 = *(const bf16x8*)&KT[(dt*16 + l)*72 + f*32 + q4*8];
                acc[dt] = __builtin_amdgcn_mfma_f32_16x16x32_bf16(af, bf2, acc[dt], 0, 0, 0);
            }
        }
    }

    // C layout: col=l (d), row=q4*4+reg (c)
    #pragma unroll
    for (int dt=0; dt<4; dt++)
        #pragma unroll
        for (int reg=0; reg<4; reg++)
            fcp[((size_t)((ns*NB + b)*256 + c0 + w*16 + q4*4 + reg))*256 + d0 + dt*16 + l] = acc[dt][reg];
}

// ======================================================================
// row softmax over f_c (sums nsegs n-partials, rows of 256) -> bf16 out
// ======================================================================
__global__ __launch_bounds__(256) void softmax_fc_kernel(
    const float* __restrict__ fcp, u16* __restrict__ pcb, int nsegs)
{
    __shared__ float red[8];
    const int tid = threadIdx.x;
    const int b = blockIdx.x >> 8, c = blockIdx.x & 255;
    float v = 0.f;
    for (int s=0; s<nsegs; s++)
        v += fcp[((size_t)((s*NB + b)*256 + c))*256 + tid];
    float m = v;
    #pragma unroll
    for (int d=32; d>=1; d>>=1) m = fmaxf(m, __shfl_xor(m, d));
    if ((tid & 63) == 0) red[tid>>6] = m;
    __syncthreads();
    m = fmaxf(fmaxf(red[0],red[1]), fmaxf(red[2],red[3]));
    float e = __expf(v - m);
    float s = e;
    #pragma unroll
    for (int d=32; d>=1; d>>=1) s += __shfl_xor(s, d);
    if ((tid & 63) == 0) red[4 + (tid>>6)] = s;
    __syncthreads();
    s = red[4]+red[5]+red[6]+red[7];
    pcb[(size_t)b*65536 + (size_t)c*256 + tid] = f2b(e / s);
}

// ======================================================================
// yc via MFMA: y_c[n][d] = sum_o V[n][o]*pc[o][d], bf16 in/out.
// ======================================================================
__global__ __launch_bounds__(256) void yc_mfma_kernel(
    const u16* __restrict__ VT, const u16* __restrict__ pcb, u16* __restrict__ ycb)
{
    __shared__ __align__(16) u16 Vl[64*32];    // [64 n][32 o], slot = (o>>3)^(n&3)
    __shared__ __align__(16) u16 Pcl[64*32];   // [64 d][32 o], slot = (o>>3)^(d&3)
    const int tid = threadIdx.x;
    const int w = tid >> 6, lane = tid & 63;
    const int q4 = lane >> 4, l = lane & 15;
    const int n0 = blockIdx.x * 64, d0 = blockIdx.y * 64, b = blockIdx.z;

    f32x4 acc[4];
    #pragma unroll
    for (int dt=0; dt<4; dt++) acc[dt] = (f32x4){0.f,0.f,0.f,0.f};

    const int so = tid >> 3;       // o-row 0..31
    const int sj = tid & 7;        // 8-col group

    for (int oc=0; oc<8; oc++){
        const int o0 = oc*32;
        __syncthreads();
        {
            uint4 v = *(const uint4*)(VT + ((size_t)(b*IC + o0 + so))*NPOS + n0 + sj*8);
            u16 tv[8]; *(uint4*)tv = v;
            #pragma unroll
            for (int m=0;m<8;m++){
                int n = sj*8 + m;
                Vl[n*32 + ((((so>>3) ^ (n&3)))<<3) + (so&7)] = tv[m];
            }
            uint4 pv = *(const uint4*)(pcb + (size_t)b*65536 + (size_t)(o0 + so)*256 + d0 + sj*8);
            u16 tp[8]; *(uint4*)tp = pv;
            #pragma unroll
            for (int m=0;m<8;m++){
                int d = sj*8 + m;
                Pcl[d*32 + ((((so>>3) ^ (d&3)))<<3) + (so&7)] = tp[m];
            }
        }
        __syncthreads();
        bf16x8 af = *(const bf16x8*)&Vl[(w*16 + l)*32 + ((q4 ^ (l&3))<<3)];
        #pragma unroll
        for (int dt=0; dt<4; dt++){
            bf16x8 bfr = *(const bf16x8*)&Pcl[(dt*16 + l)*32 + ((q4 ^ (l&3))<<3)];
            acc[dt] = __builtin_amdgcn_mfma_f32_16x16x32_bf16(af, bfr, acc[dt], 0, 0, 0);
        }
    }

    // C: row n = w*16 + q4*4 + reg, col d = d0 + dt*16 + l
    #pragma unroll
    for (int dt=0; dt<4; dt++)
        #pragma unroll
        for (int reg=0; reg<4; reg++)
            ycb[((size_t)(b*NPOS + n0 + w*16 + q4*4 + reg))*IC + d0 + dt*16 + l] = f2b(acc[dt][reg]);
}

// ======================================================================
// MFMA flash attention v7: Bk=32 tiles -> LDS 37 KB -> 4 blocks/CU
// (16 waves/CU, 2x R5 occupancy). Same proven counted-vmcnt schedule,
// XCD batch pinning, swizzles, nontemporal Q/O. vmcnt counts 8 -> 4.
// ======================================================================
__global__ __launch_bounds__(256) void flash_mfma_kernel(
    const u16* __restrict__ Q, const u16* __restrict__ K, const u16* __restrict__ VT,
    u16* __restrict__ opart0, u16* __restrict__ opartx, float* __restrict__ lpart,
    int sshift)
{
    __shared__ __align__(16) u32 lds[9472];   // 37 KB: Kt 16K | Vt 16K | P 5K
    u32* Kt = lds;                            // [32 key][256 ch], 16B-chunk swz
    u32* Vt = lds + 4096;                     // [256 d][32 key], 16B-chunk swz
    u16* Pl = (u16*)(lds + 8192);             // 4 waves x [16 m][40] u16
    const int tid  = threadIdx.x;
    const int w    = tid >> 6;
    const int lane = tid & 63;
    const int q4   = lane >> 4;
    const int l    = lane & 15;
    const int S    = 1 << sshift;

    // XCD-aware decode (R5-proven): id&7 = XCD, one batch per XCD pair
    const int id   = blockIdx.x;
    const int xcd  = id & 7;
    const int b    = xcd >> 1;                 // NB==4
    const int h    = xcd & 1;
    const int r    = id >> 3;                  // [0, 32*S)
    const int n0   = ((r & 31) | (h << 5)) * 64;
    const int seg  = r >> 5;                   // [0, S)
    const int tiles = 128 >> sshift;           // 32-key tiles per segment
    const int kt0   = seg * tiles;

    bf16x8 qf[8];
    {
        const u16* qrow = Q + ((size_t)(b*NPOS + n0 + w*16 + l))*IC;
        #pragma unroll
        for (int f=0; f<8; f++){
            u32x4 qv = __builtin_nontemporal_load((const u32x4*)(qrow + f*32 + q4*8));
            qf[f] = *(bf16x8*)&qv;
        }
    }

    f32x4 oacc[16];
    #pragma unroll
    for (int t=0;t<16;t++) oacc[t] = (f32x4){0.f,0.f,0.f,0.f};
    float lrow[4] = {0.f, 0.f, 0.f, 0.f};

    u16* Pz = Pl + w*640;   // wave-private P zone: [16 m][40] u16

    // ---- staging helpers: 4 global_load_lds x 16B per wave each ----
    auto stage_k = [&](int m0s){
        #pragma unroll
        for (int j=0;j<4;j++){
            int call = w*4 + j;                  // 0..15, 1 KB each
            int rr = call*2 + (lane>>5);         // key row 0..31
            int c = (lane & 31) ^ (rr & 7);      // 16B chunk of 512B row
            const u16* g = K + ((size_t)(b*NPOS + m0s + rr))*IC + c*8;
            __builtin_amdgcn_global_load_lds(
                (const __attribute__((address_space(1))) u32*)(const void*)g,
                (__attribute__((address_space(3))) u32*)(void*)&Kt[call*256], 16, 0, 0);
        }
    };
    auto stage_v = [&](int m0s){
        #pragma unroll
        for (int j=0;j<4;j++){
            int call = w*4 + j;                  // 0..15, 1 KB each
            int d = call*16 + (lane>>2);         // d row 0..255
            int c = (lane & 3) ^ (d & 3);        // 16B chunk of 64B row
            const u16* g = VT + ((size_t)(b*IC + d))*NPOS + m0s + c*8;
            __builtin_amdgcn_global_load_lds(
                (const __attribute__((address_space(1))) u32*)(const void*)g,
                (__attribute__((address_space(3))) u32*)(void*)&Vt[call*256], 16, 0, 0);
        }
    };

    // ---- prologue: stage tile 0 fully ----
    stage_k(kt0*32);
    stage_v(kt0*32);
    asm volatile("s_waitcnt vmcnt(0)" ::: "memory");
    __builtin_amdgcn_sched_barrier(0);
    __builtin_amdgcn_s_barrier();
    __builtin_amdgcn_sched_barrier(0);

    for (int kti=0; kti<tiles; kti++){
        const bool more = (kti + 1 < tiles);
        const int mn = (kt0 + kti + 1)*32;

        // ---- S = Q K^T  (2 key-tiles of 16, 8 k-steps of 32) ----
        f32x4 sac[2];
        sac[0] = (f32x4){0.f,0.f,0.f,0.f};
        sac[1] = (f32x4){0.f,0.f,0.f,0.f};
        __builtin_amdgcn_s_setprio(1);
        #pragma unroll
        for (int f=0; f<8; f++){
            #pragma unroll
            for (int t=0;t<2;t++){
                int rr = t*16 + l;
                int c = (f*4 + q4) ^ (rr & 7);
                bf16x8 kf = *(const bf16x8*)((const u16*)Kt + rr*256 + c*8);
                sac[t] = __builtin_amdgcn_mfma_f32_16x16x32_bf16(qf[f], kf, sac[t], 0, 0, 0);
            }
        }
        __builtin_amdgcn_s_setprio(0);

        __builtin_amdgcn_sched_barrier(0);
        __builtin_amdgcn_s_barrier();            // A: all waves done reading Kt
        __builtin_amdgcn_sched_barrier(0);

        if (more) stage_k(mn);                   // K(t+1) flies during exp + PV

        // ---- P = exp(S), wave-private [16 m][40] ----
        #pragma unroll
        for (int reg=0; reg<4; reg++){
            float p0 = __expf(sac[0][reg]), p1 = __expf(sac[1][reg]);
            lrow[reg] += p0 + p1;
            int m = q4*4 + reg;
            Pz[m*40 + l]      = f2b(p0);
            Pz[m*40 + 16 + l] = f2b(p1);
        }

        if (more) { asm volatile("s_waitcnt vmcnt(4)" ::: "memory"); }
        else      { asm volatile("s_waitcnt vmcnt(0)" ::: "memory"); }
        __builtin_amdgcn_sched_barrier(0);
        __builtin_amdgcn_s_barrier();            // B: V(t) visible to all waves
        __builtin_amdgcn_sched_barrier(0);

        // ---- O += P V  (16 d-tiles, 1 k-step of 32) ----
        __builtin_amdgcn_s_setprio(1);
        {
            bf16x8 pa = *(const bf16x8*)(Pz + l*40 + q4*8);
            #pragma unroll
            for (int t=0;t<16;t++){
                int d = t*16 + l;
                int cc = q4 ^ (d & 3);
                bf16x8 vb = *(const bf16x8*)((const u16*)Vt + d*32 + cc*8);
                oacc[t] = __builtin_amdgcn_mfma_f32_16x16x32_bf16(pa, vb, oacc[t], 0, 0, 0);
            }
        }
        __builtin_amdgcn_s_setprio(0);

        __builtin_amdgcn_sched_barrier(0);
        __builtin_amdgcn_s_barrier();            // C: all waves done reading Vt
        __builtin_amdgcn_sched_barrier(0);

        if (more) {
            stage_v(mn);                         // V(t+1) flies during S(t+1)
            asm volatile("s_waitcnt vmcnt(4)" ::: "memory");
        } else {
            asm volatile("s_waitcnt vmcnt(0)" ::: "memory");
        }
        __builtin_amdgcn_sched_barrier(0);
        __builtin_amdgcn_s_barrier();            // D: K(t+1) visible to all waves
        __builtin_amdgcn_sched_barrier(0);
    }

    // ---- l reduction across the 16 l-lanes (once, not per tile) ----
    #pragma unroll
    for (int reg=0; reg<4; reg++){
        float v = lrow[reg];
        v += __shfl_xor(v, 1); v += __shfl_xor(v, 2);
        v += __shfl_xor(v, 4); v += __shfl_xor(v, 8);
        if (l == 0)
            lpart[((size_t)(seg*NB + b))*NPOS + n0 + w*16 + q4*4 + reg] = v;
    }

    // ---- epilogue: transpose unnormalized O via wave-private zones ----
    __syncthreads();
    u16* Ez = (u16*)lds + w*4096;   // 8 KB per wave over Kt+Vt (32 KB)
    #pragma unroll
    for (int t=0;t<16;t++)
        #pragma unroll
        for (int reg=0;reg<4;reg++)
            Ez[(t*16 + l)*16 + q4*4 + reg] = f2b(oacc[t][reg]);
    u16* base = (seg == 0) ? opart0 : (opartx + (size_t)(seg-1)*((size_t)NB*IC*NPOS));
    u16* dst = base + (size_t)b*(IC*NPOS) + n0 + w*16;
    for (int p=0; p<32; p++){
        int d = p*8 + (lane>>3);
        u32 val = *(const u32*)(Ez + d*16 + (lane&7)*2);
        __builtin_nontemporal_store(val, (u32*)(dst + (size_t)d*NPOS + (lane&7)*2));
    }
}

// ======================================================================
// z = x + gs*(Ws@y_s + Ws_b) + gc*(Wc@y_c + Wc_b)   (fp32 out to d_out)
// LDS-staged fused combine (R8-proven).
// ======================================================================
__global__ __launch_bounds__(256) void z_kernel(
    const float* __restrict__ x,
    const u16* __restrict__ opart0, const u16* __restrict__ opartx,
    const float* __restrict__ lpart, int S,
    const u16* __restrict__ ycb,
    const float* __restrict__ wswT, const float* __restrict__ wcwT,
    const float* __restrict__ wsb, const float* __restrict__ wcb,
    const float* __restrict__ gs, const float* __restrict__ gc,
    float* __restrict__ zout)
{
    __shared__ __align__(16) float Wsl[64*32];
    __shared__ __align__(16) float Wcl[64*32];
    __shared__ __align__(16) float rlL[256];
    __shared__ __align__(16) u16 ysl[32*264];   // [32 i][256 p] stride 264
    __shared__ __align__(16) u16 ycl[32*264];
    const int tid = threadIdx.x;
    const int p = blockIdx.x * 256 + tid;
    const int cbase = blockIdx.y * 32;
    const int b = blockIdx.z;
    {
        int i = tid >> 2, c8 = (tid & 3) * 8;
        const float* s1 = wswT + i*64 + cbase + c8;
        const float* s2 = wcwT + i*64 + cbase + c8;
        *(float4*)&Wsl[i*32 + c8]     = *(const float4*)s1;
        *(float4*)&Wsl[i*32 + c8 + 4] = *(const float4*)(s1+4);
        *(float4*)&Wcl[i*32 + c8]     = *(const float4*)s2;
        *(float4*)&Wcl[i*32 + c8 + 4] = *(const float4*)(s2+4);
    }
    // softmax denominator: depends only on n = p & 4095
    {
        float Ls = 0.f;
        for (int s=0; s<S; s++)
            Ls += lpart[((size_t)(s*NB + b))*NPOS + (p & 4095)];
        rlL[tid] = 1.f / Ls;
    }

    float as[32], ac[32];
    #pragma unroll
    for (int c=0;c<32;c++){ as[c]=0.f; ac[c]=0.f; }

    const size_t CHUNK = (size_t)NB*IC*NPOS;
    const size_t bbase = (size_t)b*(IC*NPOS) + (size_t)blockIdx.x*256;

    for (int half=0; half<2; half++){
        __syncthreads();   // W/rlL ready (first iter); prior LDS reads done (second)
        #pragma unroll
        for (int k=0;k<4;k++){
            int ci  = tid + k*256;         // 0..1023
            int il  = ci >> 5;             // 0..31
            int i   = half*32 + il;        // z-channel 0..63
            int oct = ci & 31;             // 8-p group
            size_t gidx = bbase + (size_t)i*HW + oct*8;
            float y8[8] = {0,0,0,0,0,0,0,0};
            for (int s=0;s<S;s++){
                const u16* psrc = (s==0) ? opart0 : (opartx + (size_t)(s-1)*CHUNK);
                uint4 v = *(const uint4*)(psrc + gidx);
                y8[0]+=blo(v.x); y8[1]+=bhi(v.x); y8[2]+=blo(v.y); y8[3]+=bhi(v.y);
                y8[4]+=blo(v.z); y8[5]+=bhi(v.z); y8[6]+=blo(v.w); y8[7]+=bhi(v.w);
            }
            u32 pk[4];
            #pragma unroll
            for (int j=0;j<4;j++){
                float a0 = y8[2*j]   * rlL[oct*8 + 2*j];
                float a1 = y8[2*j+1] * rlL[oct*8 + 2*j+1];
                pk[j] = (u32)f2b(a0) | ((u32)f2b(a1) << 16);
            }
            *(uint4*)&ysl[il*264 + oct*8] = *(uint4*)pk;
            uint4 vc = *(const uint4*)(ycb + gidx);
            *(uint4*)&ycl[il*264 + oct*8] = vc;
        }
        __syncthreads();
        for (int il=0; il<32; il++){
            int i = half*32 + il;
            float ysv = b2f(ysl[il*264 + tid]);
            float ycv = b2f(ycl[il*264 + tid]);
            #pragma unroll
            for (int c=0;c<32;c++){
                as[c] = fmaf(Wsl[i*32+c], ysv, as[c]);
                ac[c] = fmaf(Wcl[i*32+c], ycv, ac[c]);
            }
        }
    }

    float gsv = gs[0], gcv = gc[0];
    #pragma unroll
    for (int c=0;c<32;c++){
        int cg = cbase + c;
        float xv = x[((size_t)b*CH + cg)*HW + p];
        float zv = fmaf(gsv, as[c] + wsb[cg], xv);
        zv = fmaf(gcv, ac[c] + wcb[cg], zv);
        zout[((size_t)b*CH + cg)*HW + p] = zv;
    }
}

// ======================================================================
// conv3x3 (64->16) + ReLU. 128 px x 2 o-halves per 256-thr block.
// ======================================================================
__global__ __launch_bounds__(256) void conv1_kernel(
    const float* __restrict__ z, const float* __restrict__ m1wT, const float* __restrict__ m1b,
    float* __restrict__ hmid)
{
    const int tid = threadIdx.x;
    const int p = blockIdx.x * 128 + (tid & 127);
    const int oh = (tid >> 7) * 8;
    const int b = blockIdx.y;
    const int y = p >> 7, xx = p & 127;
    float acc[8];
    #pragma unroll
    for (int o=0;o<8;o++) acc[o]=0.f;
    for (int c=0;c<64;c++){
        const float* zp = z + ((size_t)b*CH + c)*HW;
        #pragma unroll
        for (int t=0;t<9;t++){
            int dy = t/3 - 1, dx = t%3 - 1;
            int yy = y + dy, xv = xx + dx;
            float zv = 0.f;
            if (yy >= 0 && yy < 128 && xv >= 0 && xv < 128) zv = zp[yy*128 + xv];
            const float* w = m1wT + (c*9 + t)*16 + oh;
            #pragma unroll
            for (int o=0;o<8;o++) acc[o] = fmaf(w[o], zv, acc[o]);
        }
    }
    #pragma unroll
    for (int o=0;o<8;o++)
        hmid[((size_t)b*16 + oh + o)*HW + p] = fmaxf(acc[o] + m1b[oh + o], 0.f);
}

// ======================================================================
// conv3x3 (16->1), logit out (fp32)
// ======================================================================
__global__ __launch_bounds__(256) void conv2_kernel(
    const float* __restrict__ hmid, const float* __restrict__ m2w, const float* __restrict__ m2b,
    float* __restrict__ logit)
{
    const int idx = blockIdx.x * 256 + threadIdx.x;
    const int b = idx >> 14, p = idx & 16383;
    const int y = p >> 7, xx = p & 127;
    float acc = 0.f;
    for (int c=0;c<16;c++){
        const float* hp = hmid + ((size_t)b*16 + c)*HW;
        #pragma unroll
        for (int t=0;t<9;t++){
            int dy = t/3 - 1, dx = t%3 - 1;
            int yy = y + dy, xv = xx + dx;
            if (yy >= 0 && yy < 128 && xv >= 0 && xv < 128)
                acc = fmaf(m2w[c*9+t], hp[yy*128 + xv], acc);
        }
    }
    logit[idx] = acc + m2b[0];
}

// ======================================================================
extern "C" void kernel_launch(void* const* d_in, const int* in_sizes, int n_in,
                              void* d_out, int out_size, void* d_ws, size_t ws_size,
                              hipStream_t stream)
{
    const float* x    = (const float*)d_in[0];
    const float* g_w  = (const float*)d_in[1];
    const float* g_b  = (const float*)d_in[2];
    const float* th_w = (const float*)d_in[3];
    const float* th_b = (const float*)d_in[4];
    const float* ph_w = (const float*)d_in[5];
    const float* ph_b = (const float*)d_in[6];
    const float* ws_w = (const float*)d_in[7];
    const float* ws_b = (const float*)d_in[8];
    const float* wc_w = (const float*)d_in[9];
    const float* wc_b = (const float*)d_in[10];
    const float* gs   = (const float*)d_in[11];
    const float* gc   = (const float*)d_in[12];
    const float* m1w  = (const float*)d_in[13];
    const float* m1b  = (const float*)d_in[14];
    const float* m2w  = (const float*)d_in[15];
    const float* m2b  = (const float*)d_in[16];

    char* ws = (char*)d_ws;
    u16*   Qb   = (u16*)  (ws + 0);
    u16*   Kb   = (u16*)  (ws + 8388608);
    u16*   VTb  = (u16*)  (ws + 16777216);
    u16*   ysT  = (u16*)  (ws + 25165824);   // opart0
    u16*   ycb  = (u16*)  (ws + 33554432);
    u16*   wbf  = (u16*)  (ws + 41943040);
    u16*   pcb  = (u16*)  (ws + 42991616);   // 512 KB bf16 softmax weights
    float* fcp4 = (float*)(ws + 44040192);   // legacy 4-seg partials (sshift==0)
    float* hmid = (float*)(ws + 44040192);
    float* lpart= (float*)(ws + 44040192);   // used during flash window + z only
    float* wswT = (float*)(ws + 48234496);
    float* wcwT = (float*)(ws + 48250880);
    float* m1wT = (float*)(ws + 48267264);
    u16*   opartx = (u16*)(ws + 48304128);   // (S-1) x 8MB segments (flash window)

    float* logit = (float*)d_out;
    float* zout  = (float*)d_out + 65536;

    // choose split-K factor by available workspace (constant per session)
    int sshift = 0;
    if (ws_size >= 48304128ULL + 3ULL*8388608ULL)      sshift = 2;
    else if (ws_size >= 48304128ULL + 1ULL*8388608ULL) sshift = 1;

    // fc split-n config: 8 segs in the (pre-flash-dead) opartx region when
    // available; legacy 4 segs in the 4MB region otherwise.
    int nslg = (sshift >= 1) ? 3 : 2;
    float* fcp = (sshift >= 1) ? (float*)(ws + 48304128) : fcp4;

    prep_kernel<<<256, 256, 0, stream>>>(ws_w, wc_w, m1w, th_w, ph_w, g_w,
                                         wswT, wcwT, m1wT, wbf);
    qkv_mfma_kernel<<<dim3(64,4,3), 256, 0, stream>>>(x, wbf, th_b, ph_b, g_b, Qb, Kb, VTb);
    fc_mfma_kernel<<<dim3(4,4,NB << nslg), 256, 0, stream>>>(Qb, Kb, fcp, nslg);
    softmax_fc_kernel<<<1024, 256, 0, stream>>>(fcp, pcb, 1 << nslg);
    yc_mfma_kernel<<<dim3(64,4,4), 256, 0, stream>>>(VTb, pcb, ycb);
    flash_mfma_kernel<<<dim3(NB * 64 * (1 << sshift)), 256, 0, stream>>>(Qb, Kb, VTb, ysT, opartx, lpart, sshift);
    z_kernel<<<dim3(64,2,4), 256, 0, stream>>>(x, ysT, opartx, lpart, 1 << sshift, ycb,
                                               wswT, wcwT, ws_b, wc_b, gs, gc, zout);
    conv1_kernel<<<dim3(128,4), 256, 0, stream>>>(zout, m1wT, m1b, hmid);
    conv2_kernel<<<256, 256, 0, stream>>>(hmid, m2w, m2b, logit);
}

// Round 11
// 409.512 us; speedup vs baseline: 1.0437x; 1.0437x over previous
//
#include <hip/hip_runtime.h>
#include <stdint.h>

typedef unsigned short u16;
typedef unsigned int   u32;

typedef __attribute__((ext_vector_type(8)))  short bf16x8;
typedef __attribute__((ext_vector_type(4)))  float f32x4;
typedef __attribute__((ext_vector_type(4)))  unsigned int u32x4;

// ---------- bf16 helpers (raw ushort representation) ----------
__device__ __forceinline__ float b2f(u16 u) { return __uint_as_float(((u32)u) << 16); }
__device__ __forceinline__ float blo(u32 u) { return __uint_as_float(u << 16); }
__device__ __forceinline__ float bhi(u32 u) { return __uint_as_float(u & 0xffff0000u); }
__device__ __forceinline__ u16 f2b(float f) {
    u32 x = __float_as_uint(f);
    u32 r = (x + 0x7fffu + ((x >> 16) & 1u)) >> 16;
    return (u16)r;
}

#define NB   4
#define IC   256
#define NPOS 4096
#define CH   64
#define HW   16384

// ======================================================================
// prep: transpose small weights (fp32) + cast QKV weights to bf16
// ======================================================================
__global__ __launch_bounds__(256) void prep_kernel(
    const float* __restrict__ wsw, const float* __restrict__ wcw,
    const float* __restrict__ m1w,
    const float* __restrict__ thw, const float* __restrict__ phw, const float* __restrict__ gw,
    float* __restrict__ wswT, float* __restrict__ wcwT, float* __restrict__ m1wT,
    u16* __restrict__ wbf)
{
    int idx = blockIdx.x * 256 + threadIdx.x;
    if (idx < 65536) {
        wbf[idx]          = f2b(thw[idx]);
        wbf[idx + 65536]  = f2b(phw[idx]);
        wbf[idx + 131072] = f2b(gw[idx]);
    }
    if (idx < 4096) {
        int i = idx >> 6, c = idx & 63;
        wswT[i*64 + c] = wsw[c*64 + i];   // [i][c]: per-i rows contiguous
        wcwT[i*64 + c] = wcw[c*64 + i];
    }
    if (idx < 9216) {
        int o = idx & 15, ct = idx >> 4;
        int t = ct % 9, c = ct / 9;
        m1wT[idx] = m1w[(o*64 + c)*9 + t]; // [(c,t)][o]: 16 contiguous per tap
    }
}

// ======================================================================
// QKV via MFMA. One block: one of {Q,K,V} x [256 o][64 n] tile, K=256.
// v2: float4-vectorized x staging (16 vec loads/thread vs 64 scalar).
// ======================================================================
__global__ __launch_bounds__(256) void qkv_mfma_kernel(
    const float* __restrict__ x, const u16* __restrict__ wbf,
    const float* __restrict__ thb, const float* __restrict__ phb, const float* __restrict__ gb,
    u16* __restrict__ Q, u16* __restrict__ K, u16* __restrict__ VT)
{
    __shared__ __align__(16) u32 xT[64*132];     // 33 KB, reused for epilogue transpose
    __shared__ __align__(16) float bias_l[256];
    const int tid  = threadIdx.x;
    const int w    = tid >> 6;
    const int lane = tid & 63;
    const int q4   = lane >> 4;
    const int l    = lane & 15;
    const int n0   = blockIdx.x * 64;
    const int b    = blockIdx.y;
    const int mat  = blockIdx.z;
    const u16* wmat = wbf + mat * 65536;
    const float* bias = (mat == 0) ? thb : (mat == 1) ? phb : gb;

    bias_l[tid] = bias[tid];

    // ---- stage x tile: u16 view xT16[n*264 + i] = bf16(x[b][i][n0+n]) ----
    {
        u16* xT16 = (u16*)xT;
        const int rq = tid >> 4;        // row-subgroup 0..15
        const int nq = tid & 15;        // n-quad 0..15
        const float* xb = x + ((size_t)b*IC)*NPOS + n0 + nq*4;
        #pragma unroll 4
        for (int p2=0; p2<16; p2++){
            int i = p2*16 + rq;         // channel row 0..255
            float4 v = *(const float4*)(xb + (size_t)i*NPOS);
            xT16[(nq*4+0)*264 + i] = f2b(v.x);
            xT16[(nq*4+1)*264 + i] = f2b(v.y);
            xT16[(nq*4+2)*264 + i] = f2b(v.z);
            xT16[(nq*4+3)*264 + i] = f2b(v.w);
        }
    }
    __syncthreads();

    f32x4 acc[4][4];
    #pragma unroll
    for (int ot=0; ot<4; ot++)
        #pragma unroll
        for (int nt=0; nt<4; nt++) acc[ot][nt] = (f32x4){0.f,0.f,0.f,0.f};

    // ---- K-loop: 8 steps of 32 ----
    #pragma unroll
    for (int f=0; f<8; f++){
        bf16x8 bfrag[4];
        #pragma unroll
        for (int nt=0; nt<4; nt++)
            bfrag[nt] = *(const bf16x8*)&xT[(nt*16 + l)*132 + f*16 + q4*4];
        #pragma unroll
        for (int ot=0; ot<4; ot++){
            bf16x8 afrag = *(const bf16x8*)(wmat + (size_t)(w*64 + ot*16 + l)*256 + f*32 + q4*8);
            #pragma unroll
            for (int nt=0; nt<4; nt++)
                acc[ot][nt] = __builtin_amdgcn_mfma_f32_16x16x32_bf16(afrag, bfrag[nt], acc[ot][nt], 0, 0, 0);
        }
    }
    __syncthreads();   // xT B-frag reads done; reuse buffer for transpose

    if (mat < 2){
        // ---- Q/K: transpose to [n][o] (stride 264 u16), coalesced store ----
        u16* zbuf = (u16*)xT;
        #pragma unroll
        for (int nt=0; nt<4; nt++)
            #pragma unroll
            for (int ot=0; ot<4; ot++){
                int o = w*64 + ot*16 + q4*4;
                float4 bv = *(const float4*)&bias_l[o];
                uint2 pk;
                pk.x = (u32)f2b(acc[ot][nt][0]+bv.x) | ((u32)f2b(acc[ot][nt][1]+bv.y) << 16);
                pk.y = (u32)f2b(acc[ot][nt][2]+bv.z) | ((u32)f2b(acc[ot][nt][3]+bv.w) << 16);
                *(uint2*)&zbuf[(nt*16 + l)*264 + o] = pk;
            }
        __syncthreads();
        u16* dst = ((mat == 0) ? Q : K) + ((size_t)(b*NPOS + n0))*IC;
        int n = tid >> 2, o0 = (tid & 3)*64;
        const u32* src = &xT[n*132 + (tid & 3)*32];
        #pragma unroll
        for (int m=0; m<8; m++)
            *(uint4*)(dst + (size_t)n*IC + o0 + m*8) = ((const uint4*)src)[m];
    } else {
        // ---- V: transpose to [o][n] (stride 66 u16), store VT rows ----
        u16* zbuf = (u16*)xT;
        #pragma unroll
        for (int nt=0; nt<4; nt++)
            #pragma unroll
            for (int ot=0; ot<4; ot++){
                int o = w*64 + ot*16 + q4*4;
                int n = nt*16 + l;
                #pragma unroll
                for (int reg=0; reg<4; reg++)
                    zbuf[(o+reg)*66 + n] = f2b(acc[ot][nt][reg] + bias_l[o+reg]);
            }
        __syncthreads();
        const u32* src = &xT[tid*33];
        u32 tmp[32];
        #pragma unroll
        for (int m=0; m<32; m++) tmp[m] = src[m];
        u16* dst = VT + ((size_t)(b*IC + tid))*NPOS + n0;
        #pragma unroll
        for (int m=0; m<8; m++){
            uint4 v; v.x = tmp[m*4]; v.y = tmp[m*4+1]; v.z = tmp[m*4+2]; v.w = tmp[m*4+3];
            *(uint4*)(dst + m*8) = v;
        }
    }
}

// ======================================================================
// fc via MFMA: fc[c][d] = sum_n Q[n][c]*K[n][d]. Split-n partials.
// nsegs split-n (8 when workspace allows) for 2 blocks/CU.
// ======================================================================
__global__ __launch_bounds__(256) void fc_mfma_kernel(
    const u16* __restrict__ Q, const u16* __restrict__ K, float* __restrict__ fcp,
    int nslg)
{
    __shared__ __align__(16) u16 QT[64*72];   // 9 KB each, stride 72 (b128-aligned)
    __shared__ __align__(16) u16 KT[64*72];
    const int tid = threadIdx.x;
    const int w   = tid >> 6;
    const int lane = tid & 63;
    const int q4  = lane >> 4;
    const int l   = lane & 15;
    const int c0  = blockIdx.x * 64;
    const int d0  = blockIdx.y * 64;
    const int b   = blockIdx.z >> nslg;
    const int ns  = blockIdx.z & ((1 << nslg) - 1);
    const int chunks = 64 >> nslg;

    f32x4 acc[4];
    #pragma unroll
    for (int dt=0; dt<4; dt++) acc[dt] = (f32x4){0.f,0.f,0.f,0.f};

    for (int chunk=0; chunk<chunks; chunk++){
        const int n0 = (ns*chunks + chunk)*64;
        __syncthreads();
        {   // stage Q/K tiles transposed: [c|d][n], 16 cols per thread
            int r  = tid >> 2;            // n within chunk
            int cq = (tid & 3) * 16;
            const u16* qs = Q + ((size_t)(b*NPOS + n0 + r))*IC + c0 + cq;
            const u16* ks = K + ((size_t)(b*NPOS + n0 + r))*IC + d0 + cq;
            u16 qv[16], kv[16];
            *(uint4*)&qv[0] = *(const uint4*)qs;
            *(uint4*)&qv[8] = *(const uint4*)(qs + 8);
            *(uint4*)&kv[0] = *(const uint4*)ks;
            *(uint4*)&kv[8] = *(const uint4*)(ks + 8);
            #pragma unroll
            for (int j=0;j<16;j++){
                QT[(cq+j)*72 + r] = qv[j];
                KT[(cq+j)*72 + r] = kv[j];
            }
        }
        __syncthreads();
        // D[c][d] += sum_n A[c][n]*B[d][n]; 2 k-steps of 32
        #pragma unroll
        for (int f=0; f<2; f++){
            bf16x8 af = *(const bf16x8*)&QT[(w*16 + l)*72 + f*32 + q4*8];
            #pragma unroll
            for (int dt=0; dt<4; dt++){
                bf16x8 bf2 = *(const bf16x8*)&KT[(dt*16 + l)*72 + f*32 + q4*8];
                acc[dt] = __builtin_amdgcn_mfma_f32_16x16x32_bf16(af, bf2, acc[dt], 0, 0, 0);
            }
        }
    }

    // C layout: col=l (d), row=q4*4+reg (c)
    #pragma unroll
    for (int dt=0; dt<4; dt++)
        #pragma unroll
        for (int reg=0; reg<4; reg++)
            fcp[((size_t)((ns*NB + b)*256 + c0 + w*16 + q4*4 + reg))*256 + d0 + dt*16 + l] = acc[dt][reg];
}

// ======================================================================
// row softmax over f_c (sums nsegs n-partials, rows of 256) -> bf16 out
// ======================================================================
__global__ __launch_bounds__(256) void softmax_fc_kernel(
    const float* __restrict__ fcp, u16* __restrict__ pcb, int nsegs)
{
    __shared__ float red[8];
    const int tid = threadIdx.x;
    const int b = blockIdx.x >> 8, c = blockIdx.x & 255;
    float v = 0.f;
    for (int s=0; s<nsegs; s++)
        v += fcp[((size_t)((s*NB + b)*256 + c))*256 + tid];
    float m = v;
    #pragma unroll
    for (int d=32; d>=1; d>>=1) m = fmaxf(m, __shfl_xor(m, d));
    if ((tid & 63) == 0) red[tid>>6] = m;
    __syncthreads();
    m = fmaxf(fmaxf(red[0],red[1]), fmaxf(red[2],red[3]));
    float e = __expf(v - m);
    float s = e;
    #pragma unroll
    for (int d=32; d>=1; d>>=1) s += __shfl_xor(s, d);
    if ((tid & 63) == 0) red[4 + (tid>>6)] = s;
    __syncthreads();
    s = red[4]+red[5]+red[6]+red[7];
    pcb[(size_t)b*65536 + (size_t)c*256 + tid] = f2b(e / s);
}

// ======================================================================
// yc via MFMA: y_c[n][d] = sum_o V[n][o]*pc[o][d], bf16 in/out.
// ======================================================================
__global__ __launch_bounds__(256) void yc_mfma_kernel(
    const u16* __restrict__ VT, const u16* __restrict__ pcb, u16* __restrict__ ycb)
{
    __shared__ __align__(16) u16 Vl[64*32];    // [64 n][32 o], slot = (o>>3)^(n&3)
    __shared__ __align__(16) u16 Pcl[64*32];   // [64 d][32 o], slot = (o>>3)^(d&3)
    const int tid = threadIdx.x;
    const int w = tid >> 6, lane = tid & 63;
    const int q4 = lane >> 4, l = lane & 15;
    const int n0 = blockIdx.x * 64, d0 = blockIdx.y * 64, b = blockIdx.z;

    f32x4 acc[4];
    #pragma unroll
    for (int dt=0; dt<4; dt++) acc[dt] = (f32x4){0.f,0.f,0.f,0.f};

    const int so = tid >> 3;       // o-row 0..31
    const int sj = tid & 7;        // 8-col group

    for (int oc=0; oc<8; oc++){
        const int o0 = oc*32;
        __syncthreads();
        {
            uint4 v = *(const uint4*)(VT + ((size_t)(b*IC + o0 + so))*NPOS + n0 + sj*8);
            u16 tv[8]; *(uint4*)tv = v;
            #pragma unroll
            for (int m=0;m<8;m++){
                int n = sj*8 + m;
                Vl[n*32 + ((((so>>3) ^ (n&3)))<<3) + (so&7)] = tv[m];
            }
            uint4 pv = *(const uint4*)(pcb + (size_t)b*65536 + (size_t)(o0 + so)*256 + d0 + sj*8);
            u16 tp[8]; *(uint4*)tp = pv;
            #pragma unroll
            for (int m=0;m<8;m++){
                int d = sj*8 + m;
                Pcl[d*32 + ((((so>>3) ^ (d&3)))<<3) + (so&7)] = tp[m];
            }
        }
        __syncthreads();
        bf16x8 af = *(const bf16x8*)&Vl[(w*16 + l)*32 + ((q4 ^ (l&3))<<3)];
        #pragma unroll
        for (int dt=0; dt<4; dt++){
            bf16x8 bfr = *(const bf16x8*)&Pcl[(dt*16 + l)*32 + ((q4 ^ (l&3))<<3)];
            acc[dt] = __builtin_amdgcn_mfma_f32_16x16x32_bf16(af, bfr, acc[dt], 0, 0, 0);
        }
    }

    // C: row n = w*16 + q4*4 + reg, col d = d0 + dt*16 + l
    #pragma unroll
    for (int dt=0; dt<4; dt++)
        #pragma unroll
        for (int reg=0; reg<4; reg++)
            ycb[((size_t)(b*NPOS + n0 + w*16 + q4*4 + reg))*IC + d0 + dt*16 + l] = f2b(acc[dt][reg]);
}

// ======================================================================
// MFMA flash attention (R5/R8-proven, 119 us): Bq=64/Bk=64, counted
// vmcnt(8) pipeline, XCD batch pinning, nontemporal Q/O.
// LDS 74.75 KB -> 2 blocks/CU.
// ======================================================================
__global__ __launch_bounds__(256) void flash_mfma_kernel(
    const u16* __restrict__ Q, const u16* __restrict__ K, const u16* __restrict__ VT,
    u16* __restrict__ opart0, u16* __restrict__ opartx, float* __restrict__ lpart,
    int sshift)
{
    __shared__ __align__(16) u32 Kt[8192];   // 32 KB: K tile (swizzled); epilogue O zones
    __shared__ __align__(16) u32 Vt[8192];   // 32 KB: V^T tile (swizzled)
    __shared__ __align__(16) u16 Pl[4608];   // 9.25 KB: wave-private P, stride 72
    const int tid  = threadIdx.x;
    const int w    = tid >> 6;
    const int lane = tid & 63;
    const int q4   = lane >> 4;
    const int l    = lane & 15;
    const int S    = 1 << sshift;

    const int id   = blockIdx.x;
    const int xcd  = id & 7;
    const int b    = xcd >> 1;                 // NB==4
    const int h    = xcd & 1;
    const int r    = id >> 3;                  // [0, 32*S)
    const int n0   = ((r & 31) | (h << 5)) * 64;
    const int seg  = r >> 5;                   // [0, S)
    const int tiles = 64 >> sshift;
    const int kt0   = seg * tiles;

    bf16x8 qf[8];
    {
        const u16* qrow = Q + ((size_t)(b*NPOS + n0 + w*16 + l))*IC;
        #pragma unroll
        for (int f=0; f<8; f++){
            u32x4 qv = __builtin_nontemporal_load((const u32x4*)(qrow + f*32 + q4*8));
            qf[f] = *(bf16x8*)&qv;
        }
    }

    f32x4 oacc[16];
    #pragma unroll
    for (int t=0;t<16;t++) oacc[t] = (f32x4){0.f,0.f,0.f,0.f};
    float lrow[4] = {0.f, 0.f, 0.f, 0.f};

    u16* Pz = Pl + w*1152;   // wave-private P zone: rows m*72, m=0..15

    auto stage_k = [&](int m0s){
        #pragma unroll
        for (int j=0;j<8;j++){
            int call = w*8 + j;
            int rr = call*2 + (lane>>5);
            int c = (lane & 31) ^ (rr & 7);
            const u16* g = K + ((size_t)(b*NPOS + m0s + rr))*IC + c*8;
            __builtin_amdgcn_global_load_lds(
                (const __attribute__((address_space(1))) u32*)(const void*)g,
                (__attribute__((address_space(3))) u32*)(void*)&Kt[call*256], 16, 0, 0);
        }
    };
    auto stage_v = [&](int m0s){
        #pragma unroll
        for (int j=0;j<8;j++){
            int call = w*8 + j;
            int d = call*8 + (lane>>3);
            int c = (lane & 7) ^ (d & 7);
            const u16* g = VT + ((size_t)(b*IC + d))*NPOS + m0s + c*8;
            __builtin_amdgcn_global_load_lds(
                (const __attribute__((address_space(1))) u32*)(const void*)g,
                (__attribute__((address_space(3))) u32*)(void*)&Vt[call*256], 16, 0, 0);
        }
    };

    stage_k(kt0*64);
    stage_v(kt0*64);
    asm volatile("s_waitcnt vmcnt(0)" ::: "memory");
    __builtin_amdgcn_sched_barrier(0);
    __builtin_amdgcn_s_barrier();
    __builtin_amdgcn_sched_barrier(0);

    for (int kti=0; kti<tiles; kti++){
        const bool more = (kti + 1 < tiles);
        const int mn = (kt0 + kti + 1)*64;

        f32x4 sac[4];
        #pragma unroll
        for (int t=0;t<4;t++) sac[t] = (f32x4){0.f,0.f,0.f,0.f};
        __builtin_amdgcn_s_setprio(1);
        #pragma unroll
        for (int f=0; f<8; f++){
            #pragma unroll
            for (int t=0;t<4;t++){
                int rr = t*16 + l;
                int c = (f*4 + q4) ^ (rr & 7);
                bf16x8 kf = *(const bf16x8*)((const u16*)Kt + rr*256 + c*8);
                sac[t] = __builtin_amdgcn_mfma_f32_16x16x32_bf16(qf[f], kf, sac[t], 0, 0, 0);
            }
        }
        __builtin_amdgcn_s_setprio(0);

        __builtin_amdgcn_sched_barrier(0);
        __builtin_amdgcn_s_barrier();            // A: all waves done reading Kt
        __builtin_amdgcn_sched_barrier(0);

        if (more) stage_k(mn);

        #pragma unroll
        for (int reg=0; reg<4; reg++){
            float p0 = __expf(sac[0][reg]), p1 = __expf(sac[1][reg]);
            float p2 = __expf(sac[2][reg]), p3 = __expf(sac[3][reg]);
            lrow[reg] += (p0+p1) + (p2+p3);
            int m = q4*4 + reg;
            Pz[m*72 + l]      = f2b(p0);
            Pz[m*72 + 16 + l] = f2b(p1);
            Pz[m*72 + 32 + l] = f2b(p2);
            Pz[m*72 + 48 + l] = f2b(p3);
        }

        if (more) { asm volatile("s_waitcnt vmcnt(8)" ::: "memory"); }
        else      { asm volatile("s_waitcnt vmcnt(0)" ::: "memory"); }
        __builtin_amdgcn_sched_barrier(0);
        __builtin_amdgcn_s_barrier();            // B: V(t) visible to all waves
        __builtin_amdgcn_sched_barrier(0);

        __builtin_amdgcn_s_setprio(1);
        #pragma unroll
        for (int s2=0; s2<2; s2++){
            bf16x8 pa = *(const bf16x8*)(Pz + l*72 + s2*32 + q4*8);
            #pragma unroll
            for (int t=0;t<16;t++){
                int d = t*16 + l;
                int c = (s2*4 + q4) ^ (d & 7);
                bf16x8 vb = *(const bf16x8*)((const u16*)Vt + d*64 + c*8);
                oacc[t] = __builtin_amdgcn_mfma_f32_16x16x32_bf16(pa, vb, oacc[t], 0, 0, 0);
            }
        }
        __builtin_amdgcn_s_setprio(0);

        __builtin_amdgcn_sched_barrier(0);
        __builtin_amdgcn_s_barrier();            // C: all waves done reading Vt
        __builtin_amdgcn_sched_barrier(0);

        if (more) {
            stage_v(mn);
            asm volatile("s_waitcnt vmcnt(8)" ::: "memory");
        } else {
            asm volatile("s_waitcnt vmcnt(0)" ::: "memory");
        }
        __builtin_amdgcn_sched_barrier(0);
        __builtin_amdgcn_s_barrier();            // D: K(t+1) visible to all waves
        __builtin_amdgcn_sched_barrier(0);
    }

    #pragma unroll
    for (int reg=0; reg<4; reg++){
        float v = lrow[reg];
        v += __shfl_xor(v, 1); v += __shfl_xor(v, 2);
        v += __shfl_xor(v, 4); v += __shfl_xor(v, 8);
        if (l == 0)
            lpart[((size_t)(seg*NB + b))*NPOS + n0 + w*16 + q4*4 + reg] = v;
    }

    __syncthreads();
    u16* Ez = (u16*)Kt + w*4096;   // 8 KB per wave
    #pragma unroll
    for (int t=0;t<16;t++)
        #pragma unroll
        for (int reg=0;reg<4;reg++)
            Ez[(t*16 + l)*16 + q4*4 + reg] = f2b(oacc[t][reg]);
    u16* base = (seg == 0) ? opart0 : (opartx + (size_t)(seg-1)*((size_t)NB*IC*NPOS));
    u16* dst = base + (size_t)b*(IC*NPOS) + n0 + w*16;
    for (int p=0; p<32; p++){
        int d = p*8 + (lane>>3);
        u32 val = *(const u32*)(Ez + d*16 + (lane&7)*2);
        __builtin_nontemporal_store(val, (u32*)(dst + (size_t)d*NPOS + (lane&7)*2));
    }
}

// ======================================================================
// z = x + gs*(Ws@y_s + Ws_b) + gc*(Wc@y_c + Wc_b)   (fp32 out to d_out)
// LDS-staged fused combine (R8-proven).
// ======================================================================
__global__ __launch_bounds__(256) void z_kernel(
    const float* __restrict__ x,
    const u16* __restrict__ opart0, const u16* __restrict__ opartx,
    const float* __restrict__ lpart, int S,
    const u16* __restrict__ ycb,
    const float* __restrict__ wswT, const float* __restrict__ wcwT,
    const float* __restrict__ wsb, const float* __restrict__ wcb,
    const float* __restrict__ gs, const float* __restrict__ gc,
    float* __restrict__ zout)
{
    __shared__ __align__(16) float Wsl[64*32];
    __shared__ __align__(16) float Wcl[64*32];
    __shared__ __align__(16) float rlL[256];
    __shared__ __align__(16) u16 ysl[32*264];   // [32 i][256 p] stride 264
    __shared__ __align__(16) u16 ycl[32*264];
    const int tid = threadIdx.x;
    const int p = blockIdx.x * 256 + tid;
    const int cbase = blockIdx.y * 32;
    const int b = blockIdx.z;
    {
        int i = tid >> 2, c8 = (tid & 3) * 8;
        const float* s1 = wswT + i*64 + cbase + c8;
        const float* s2 = wcwT + i*64 + cbase + c8;
        *(float4*)&Wsl[i*32 + c8]     = *(const float4*)s1;
        *(float4*)&Wsl[i*32 + c8 + 4] = *(const float4*)(s1+4);
        *(float4*)&Wcl[i*32 + c8]     = *(const float4*)s2;
        *(float4*)&Wcl[i*32 + c8 + 4] = *(const float4*)(s2+4);
    }
    // softmax denominator: depends only on n = p & 4095
    {
        float Ls = 0.f;
        for (int s=0; s<S; s++)
            Ls += lpart[((size_t)(s*NB + b))*NPOS + (p & 4095)];
        rlL[tid] = 1.f / Ls;
    }

    float as[32], ac[32];
    #pragma unroll
    for (int c=0;c<32;c++){ as[c]=0.f; ac[c]=0.f; }

    const size_t CHUNK = (size_t)NB*IC*NPOS;
    const size_t bbase = (size_t)b*(IC*NPOS) + (size_t)blockIdx.x*256;

    for (int half=0; half<2; half++){
        __syncthreads();   // W/rlL ready (first iter); prior LDS reads done (second)
        #pragma unroll
        for (int k=0;k<4;k++){
            int ci  = tid + k*256;         // 0..1023
            int il  = ci >> 5;             // 0..31
            int i   = half*32 + il;        // z-channel 0..63
            int oct = ci & 31;             // 8-p group
            size_t gidx = bbase + (size_t)i*HW + oct*8;
            float y8[8] = {0,0,0,0,0,0,0,0};
            for (int s=0;s<S;s++){
                const u16* psrc = (s==0) ? opart0 : (opartx + (size_t)(s-1)*CHUNK);
                uint4 v = *(const uint4*)(psrc + gidx);
                y8[0]+=blo(v.x); y8[1]+=bhi(v.x); y8[2]+=blo(v.y); y8[3]+=bhi(v.y);
                y8[4]+=blo(v.z); y8[5]+=bhi(v.z); y8[6]+=blo(v.w); y8[7]+=bhi(v.w);
            }
            u32 pk[4];
            #pragma unroll
            for (int j=0;j<4;j++){
                float a0 = y8[2*j]   * rlL[oct*8 + 2*j];
                float a1 = y8[2*j+1] * rlL[oct*8 + 2*j+1];
                pk[j] = (u32)f2b(a0) | ((u32)f2b(a1) << 16);
            }
            *(uint4*)&ysl[il*264 + oct*8] = *(uint4*)pk;
            uint4 vc = *(const uint4*)(ycb + gidx);
            *(uint4*)&ycl[il*264 + oct*8] = vc;
        }
        __syncthreads();
        for (int il=0; il<32; il++){
            int i = half*32 + il;
            float ysv = b2f(ysl[il*264 + tid]);
            float ycv = b2f(ycl[il*264 + tid]);
            #pragma unroll
            for (int c=0;c<32;c++){
                as[c] = fmaf(Wsl[i*32+c], ysv, as[c]);
                ac[c] = fmaf(Wcl[i*32+c], ycv, ac[c]);
            }
        }
    }

    float gsv = gs[0], gcv = gc[0];
    #pragma unroll
    for (int c=0;c<32;c++){
        int cg = cbase + c;
        float xv = x[((size_t)b*CH + cg)*HW + p];
        float zv = fmaf(gsv, as[c] + wsb[cg], xv);
        zv = fmaf(gcv, ac[c] + wcb[cg], zv);
        zout[((size_t)b*CH + cg)*HW + p] = zv;
    }
}

// ======================================================================
// conv3x3 (64->16) + ReLU. 128 px x 2 o-halves per 256-thr block.
// ======================================================================
__global__ __launch_bounds__(256) void conv1_kernel(
    const float* __restrict__ z, const float* __restrict__ m1wT, const float* __restrict__ m1b,
    float* __restrict__ hmid)
{
    const int tid = threadIdx.x;
    const int p = blockIdx.x * 128 + (tid & 127);
    const int oh = (tid >> 7) * 8;
    const int b = blockIdx.y;
    const int y = p >> 7, xx = p & 127;
    float acc[8];
    #pragma unroll
    for (int o=0;o<8;o++) acc[o]=0.f;
    for (int c=0;c<64;c++){
        const float* zp = z + ((size_t)b*CH + c)*HW;
        #pragma unroll
        for (int t=0;t<9;t++){
            int dy = t/3 - 1, dx = t%3 - 1;
            int yy = y + dy, xv = xx + dx;
            float zv = 0.f;
            if (yy >= 0 && yy < 128 && xv >= 0 && xv < 128) zv = zp[yy*128 + xv];
            const float* w = m1wT + (c*9 + t)*16 + oh;
            #pragma unroll
            for (int o=0;o<8;o++) acc[o] = fmaf(w[o], zv, acc[o]);
        }
    }
    #pragma unroll
    for (int o=0;o<8;o++)
        hmid[((size_t)b*16 + oh + o)*HW + p] = fmaxf(acc[o] + m1b[oh + o], 0.f);
}

// ======================================================================
// conv3x3 (16->1), logit out (fp32)
// ======================================================================
__global__ __launch_bounds__(256) void conv2_kernel(
    const float* __restrict__ hmid, const float* __restrict__ m2w, const float* __restrict__ m2b,
    float* __restrict__ logit)
{
    const int idx = blockIdx.x * 256 + threadIdx.x;
    const int b = idx >> 14, p = idx & 16383;
    const int y = p >> 7, xx = p & 127;
    float acc = 0.f;
    for (int c=0;c<16;c++){
        const float* hp = hmid + ((size_t)b*16 + c)*HW;
        #pragma unroll
        for (int t=0;t<9;t++){
            int dy = t/3 - 1, dx = t%3 - 1;
            int yy = y + dy, xv = xx + dx;
            if (yy >= 0 && yy < 128 && xv >= 0 && xv < 128)
                acc = fmaf(m2w[c*9+t], hp[yy*128 + xv], acc);
        }
    }
    logit[idx] = acc + m2b[0];
}

// ======================================================================
extern "C" void kernel_launch(void* const* d_in, const int* in_sizes, int n_in,
                              void* d_out, int out_size, void* d_ws, size_t ws_size,
                              hipStream_t stream)
{
    const float* x    = (const float*)d_in[0];
    const float* g_w  = (const float*)d_in[1];
    const float* g_b  = (const float*)d_in[2];
    const float* th_w = (const float*)d_in[3];
    const float* th_b = (const float*)d_in[4];
    const float* ph_w = (const float*)d_in[5];
    const float* ph_b = (const float*)d_in[6];
    const float* ws_w = (const float*)d_in[7];
    const float* ws_b = (const float*)d_in[8];
    const float* wc_w = (const float*)d_in[9];
    const float* wc_b = (const float*)d_in[10];
    const float* gs   = (const float*)d_in[11];
    const float* gc   = (const float*)d_in[12];
    const float* m1w  = (const float*)d_in[13];
    const float* m1b  = (const float*)d_in[14];
    const float* m2w  = (const float*)d_in[15];
    const float* m2b  = (const float*)d_in[16];

    char* ws = (char*)d_ws;
    u16*   Qb   = (u16*)  (ws + 0);
    u16*   Kb   = (u16*)  (ws + 8388608);
    u16*   VTb  = (u16*)  (ws + 16777216);
    u16*   ysT  = (u16*)  (ws + 25165824);   // opart0
    u16*   ycb  = (u16*)  (ws + 33554432);
    u16*   wbf  = (u16*)  (ws + 41943040);
    u16*   pcb  = (u16*)  (ws + 42991616);   // 512 KB bf16 softmax weights
    float* fcp4 = (float*)(ws + 44040192);   // legacy 4-seg partials (sshift==0)
    float* hmid = (float*)(ws + 44040192);
    float* lpart= (float*)(ws + 44040192);   // used during flash window + z only
    float* wswT = (float*)(ws + 48234496);
    float* wcwT = (float*)(ws + 48250880);
    float* m1wT = (float*)(ws + 48267264);
    u16*   opartx = (u16*)(ws + 48304128);   // (S-1) x 8MB segments (flash window)

    float* logit = (float*)d_out;
    float* zout  = (float*)d_out + 65536;

    // choose split-K factor by available workspace (constant per session)
    int sshift = 0;
    if (ws_size >= 48304128ULL + 3ULL*8388608ULL)      sshift = 2;
    else if (ws_size >= 48304128ULL + 1ULL*8388608ULL) sshift = 1;

    // fc split-n config: 8 segs in the (pre-flash-dead) opartx region when
    // available; legacy 4 segs in the 4MB region otherwise.
    int nslg = (sshift >= 1) ? 3 : 2;
    float* fcp = (sshift >= 1) ? (float*)(ws + 48304128) : fcp4;

    prep_kernel<<<256, 256, 0, stream>>>(ws_w, wc_w, m1w, th_w, ph_w, g_w,
                                         wswT, wcwT, m1wT, wbf);
    qkv_mfma_kernel<<<dim3(64,4,3), 256, 0, stream>>>(x, wbf, th_b, ph_b, g_b, Qb, Kb, VTb);
    fc_mfma_kernel<<<dim3(4,4,NB << nslg), 256, 0, stream>>>(Qb, Kb, fcp, nslg);
    softmax_fc_kernel<<<1024, 256, 0, stream>>>(fcp, pcb, 1 << nslg);
    yc_mfma_kernel<<<dim3(64,4,4), 256, 0, stream>>>(VTb, pcb, ycb);
    flash_mfma_kernel<<<dim3(NB * 64 * (1 << sshift)), 256, 0, stream>>>(Qb, Kb, VTb, ysT, opartx, lpart, sshift);
    z_kernel<<<dim3(64,2,4), 256, 0, stream>>>(x, ysT, opartx, lpart, 1 << sshift, ycb,
                                               wswT, wcwT, ws_b, wc_b, gs, gc, zout);
    conv1_kernel<<<dim3(128,4), 256, 0, stream>>>(zout, m1wT, m1b, hmid);
    conv2_kernel<<<256, 256, 0, stream>>>(hmid, m2w, m2b, logit);
}

// Round 12
// 390.475 us; speedup vs baseline: 1.0945x; 1.0488x over previous
//
#include <hip/hip_runtime.h>
#include <stdint.h>

typedef unsigned short u16;
typedef unsigned int   u32;

typedef __attribute__((ext_vector_type(8)))  short bf16x8;
typedef __attribute__((ext_vector_type(4)))  float f32x4;
typedef __attribute__((ext_vector_type(4)))  unsigned int u32x4;

// ---------- bf16 helpers (raw ushort representation) ----------
__device__ __forceinline__ float b2f(u16 u) { return __uint_as_float(((u32)u) << 16); }
__device__ __forceinline__ float blo(u32 u) { return __uint_as_float(u << 16); }
__device__ __forceinline__ float bhi(u32 u) { return __uint_as_float(u & 0xffff0000u); }
__device__ __forceinline__ u16 f2b(float f) {
    u32 x = __float_as_uint(f);
    u32 r = (x + 0x7fffu + ((x >> 16) & 1u)) >> 16;
    return (u16)r;
}

#define NB   4
#define IC   256
#define NPOS 4096
#define CH   64
#define HW   16384

// ======================================================================
// prep: transpose small weights (fp32) + cast QKV weights to bf16
// ======================================================================
__global__ __launch_bounds__(256) void prep_kernel(
    const float* __restrict__ wsw, const float* __restrict__ wcw,
    const float* __restrict__ m1w,
    const float* __restrict__ thw, const float* __restrict__ phw, const float* __restrict__ gw,
    float* __restrict__ wswT, float* __restrict__ wcwT, float* __restrict__ m1wT,
    u16* __restrict__ wbf)
{
    int idx = blockIdx.x * 256 + threadIdx.x;
    if (idx < 65536) {
        wbf[idx]          = f2b(thw[idx]);
        wbf[idx + 65536]  = f2b(phw[idx]);
        wbf[idx + 131072] = f2b(gw[idx]);
    }
    if (idx < 4096) {
        int i = idx >> 6, c = idx & 63;
        wswT[i*64 + c] = wsw[c*64 + i];   // [i][c]: per-i rows contiguous
        wcwT[i*64 + c] = wcw[c*64 + i];
    }
    if (idx < 9216) {
        int o = idx & 15, ct = idx >> 4;
        int t = ct % 9, c = ct / 9;
        m1wT[idx] = m1w[(o*64 + c)*9 + t]; // [(c,t)][o]: 16 contiguous per tap
    }
}

// ======================================================================
// QKV via MFMA, 3-in-1: one block stages the x tile ONCE and computes
// theta/phi/g against it (x traffic 48 MB -> 16 MB). Grid (64, 4).
// Separate 33 KB epilogue buffer zb (xT preserved across mats).
// LDS = 33 + 33 + 3 KB = 69 KB.
// ======================================================================
__global__ __launch_bounds__(256) void qkv_mfma_kernel(
    const float* __restrict__ x, const u16* __restrict__ wbf,
    const float* __restrict__ thb, const float* __restrict__ phb, const float* __restrict__ gb,
    u16* __restrict__ Q, u16* __restrict__ K, u16* __restrict__ VT)
{
    __shared__ __align__(16) u32 xT[64*132];     // 33 KB: x tile (bf16 pairs)
    __shared__ __align__(16) u32 zb[64*132];     // 33 KB: epilogue scratch
    __shared__ __align__(16) float bias_l[768];
    const int tid  = threadIdx.x;
    const int w    = tid >> 6;
    const int lane = tid & 63;
    const int q4   = lane >> 4;
    const int l    = lane & 15;
    const int n0   = blockIdx.x * 64;
    const int b    = blockIdx.y;

    bias_l[tid]       = thb[tid];
    bias_l[256 + tid] = phb[tid];
    bias_l[512 + tid] = gb[tid];

    // ---- stage x tile: u16 view xT16[n*264 + i] = bf16(x[b][i][n0+n]) ----
    {
        u16* xT16 = (u16*)xT;
        const int rq = tid >> 4;        // row-subgroup 0..15
        const int nq = tid & 15;        // n-quad 0..15
        const float* xb = x + ((size_t)b*IC)*NPOS + n0 + nq*4;
        #pragma unroll 4
        for (int p2=0; p2<16; p2++){
            int i = p2*16 + rq;         // channel row 0..255
            float4 v = *(const float4*)(xb + (size_t)i*NPOS);
            xT16[(nq*4+0)*264 + i] = f2b(v.x);
            xT16[(nq*4+1)*264 + i] = f2b(v.y);
            xT16[(nq*4+2)*264 + i] = f2b(v.z);
            xT16[(nq*4+3)*264 + i] = f2b(v.w);
        }
    }
    __syncthreads();

    for (int mat=0; mat<3; mat++){
        const u16* wmat = wbf + mat * 65536;

        f32x4 acc[4][4];
        #pragma unroll
        for (int ot=0; ot<4; ot++)
            #pragma unroll
            for (int nt=0; nt<4; nt++) acc[ot][nt] = (f32x4){0.f,0.f,0.f,0.f};

        // ---- K-loop: 8 steps of 32 (reads xT only) ----
        #pragma unroll
        for (int f=0; f<8; f++){
            bf16x8 bfrag[4];
            #pragma unroll
            for (int nt=0; nt<4; nt++)
                bfrag[nt] = *(const bf16x8*)&xT[(nt*16 + l)*132 + f*16 + q4*4];
            #pragma unroll
            for (int ot=0; ot<4; ot++){
                bf16x8 afrag = *(const bf16x8*)(wmat + (size_t)(w*64 + ot*16 + l)*256 + f*32 + q4*8);
                #pragma unroll
                for (int nt=0; nt<4; nt++)
                    acc[ot][nt] = __builtin_amdgcn_mfma_f32_16x16x32_bf16(afrag, bfrag[nt], acc[ot][nt], 0, 0, 0);
            }
        }

        __syncthreads();   // prior mat's zb reads complete before overwrite

        if (mat < 2){
            // ---- Q/K: transpose to [n][o] (stride 264 u16), coalesced store ----
            u16* zbuf = (u16*)zb;
            #pragma unroll
            for (int nt=0; nt<4; nt++)
                #pragma unroll
                for (int ot=0; ot<4; ot++){
                    int o = w*64 + ot*16 + q4*4;
                    float4 bv = *(const float4*)&bias_l[mat*256 + o];
                    uint2 pk;
                    pk.x = (u32)f2b(acc[ot][nt][0]+bv.x) | ((u32)f2b(acc[ot][nt][1]+bv.y) << 16);
                    pk.y = (u32)f2b(acc[ot][nt][2]+bv.z) | ((u32)f2b(acc[ot][nt][3]+bv.w) << 16);
                    *(uint2*)&zbuf[(nt*16 + l)*264 + o] = pk;
                }
            __syncthreads();
            u16* dst = ((mat == 0) ? Q : K) + ((size_t)(b*NPOS + n0))*IC;
            int n = tid >> 2, o0 = (tid & 3)*64;
            const u32* src = &zb[n*132 + (tid & 3)*32];
            #pragma unroll
            for (int m=0; m<8; m++)
                *(uint4*)(dst + (size_t)n*IC + o0 + m*8) = ((const uint4*)src)[m];
        } else {
            // ---- V: transpose to [o][n] (stride 66 u16), store VT rows ----
            u16* zbuf = (u16*)zb;
            #pragma unroll
            for (int nt=0; nt<4; nt++)
                #pragma unroll
                for (int ot=0; ot<4; ot++){
                    int o = w*64 + ot*16 + q4*4;
                    int n = nt*16 + l;
                    #pragma unroll
                    for (int reg=0; reg<4; reg++)
                        zbuf[(o+reg)*66 + n] = f2b(acc[ot][nt][reg] + bias_l[512 + o+reg]);
                }
            __syncthreads();
            const u32* src = &zb[tid*33];
            u32 tmp[32];
            #pragma unroll
            for (int m=0; m<32; m++) tmp[m] = src[m];
            u16* dst = VT + ((size_t)(b*IC + tid))*NPOS + n0;
            #pragma unroll
            for (int m=0; m<8; m++){
                uint4 v; v.x = tmp[m*4]; v.y = tmp[m*4+1]; v.z = tmp[m*4+2]; v.w = tmp[m*4+3];
                *(uint4*)(dst + m*8) = v;
            }
        }
    }
}

// ======================================================================
// fc via MFMA: fc[c][d] = sum_n Q[n][c]*K[n][d]. Split-n partials.
// ======================================================================
__global__ __launch_bounds__(256) void fc_mfma_kernel(
    const u16* __restrict__ Q, const u16* __restrict__ K, float* __restrict__ fcp,
    int nslg)
{
    __shared__ __align__(16) u16 QT[64*72];   // 9 KB each, stride 72 (b128-aligned)
    __shared__ __align__(16) u16 KT[64*72];
    const int tid = threadIdx.x;
    const int w   = tid >> 6;
    const int lane = tid & 63;
    const int q4  = lane >> 4;
    const int l   = lane & 15;
    const int c0  = blockIdx.x * 64;
    const int d0  = blockIdx.y * 64;
    const int b   = blockIdx.z >> nslg;
    const int ns  = blockIdx.z & ((1 << nslg) - 1);
    const int chunks = 64 >> nslg;

    f32x4 acc[4];
    #pragma unroll
    for (int dt=0; dt<4; dt++) acc[dt] = (f32x4){0.f,0.f,0.f,0.f};

    for (int chunk=0; chunk<chunks; chunk++){
        const int n0 = (ns*chunks + chunk)*64;
        __syncthreads();
        {   // stage Q/K tiles transposed: [c|d][n], 16 cols per thread
            int r  = tid >> 2;            // n within chunk
            int cq = (tid & 3) * 16;
            const u16* qs = Q + ((size_t)(b*NPOS + n0 + r))*IC + c0 + cq;
            const u16* ks = K + ((size_t)(b*NPOS + n0 + r))*IC + d0 + cq;
            u16 qv[16], kv[16];
            *(uint4*)&qv[0] = *(const uint4*)qs;
            *(uint4*)&qv[8] = *(const uint4*)(qs + 8);
            *(uint4*)&kv[0] = *(const uint4*)ks;
            *(uint4*)&kv[8] = *(const uint4*)(ks + 8);
            #pragma unroll
            for (int j=0;j<16;j++){
                QT[(cq+j)*72 + r] = qv[j];
                KT[(cq+j)*72 + r] = kv[j];
            }
        }
        __syncthreads();
        // D[c][d] += sum_n A[c][n]*B[d][n]; 2 k-steps of 32
        #pragma unroll
        for (int f=0; f<2; f++){
            bf16x8 af = *(const bf16x8*)&QT[(w*16 + l)*72 + f*32 + q4*8];
            #pragma unroll
            for (int dt=0; dt<4; dt++){
                bf16x8 bf2 = *(const bf16x8*)&KT[(dt*16 + l)*72 + f*32 + q4*8];
                acc[dt] = __builtin_amdgcn_mfma_f32_16x16x32_bf16(af, bf2, acc[dt], 0, 0, 0);
            }
        }
    }

    // C layout: col=l (d), row=q4*4+reg (c)
    #pragma unroll
    for (int dt=0; dt<4; dt++)
        #pragma unroll
        for (int reg=0; reg<4; reg++)
            fcp[((size_t)((ns*NB + b)*256 + c0 + w*16 + q4*4 + reg))*256 + d0 + dt*16 + l] = acc[dt][reg];
}

// ======================================================================
// row softmax over f_c (sums nsegs n-partials, rows of 256) -> bf16 out
// ======================================================================
__global__ __launch_bounds__(256) void softmax_fc_kernel(
    const float* __restrict__ fcp, u16* __restrict__ pcb, int nsegs)
{
    __shared__ float red[8];
    const int tid = threadIdx.x;
    const int b = blockIdx.x >> 8, c = blockIdx.x & 255;
    float v = 0.f;
    for (int s=0; s<nsegs; s++)
        v += fcp[((size_t)((s*NB + b)*256 + c))*256 + tid];
    float m = v;
    #pragma unroll
    for (int d=32; d>=1; d>>=1) m = fmaxf(m, __shfl_xor(m, d));
    if ((tid & 63) == 0) red[tid>>6] = m;
    __syncthreads();
    m = fmaxf(fmaxf(red[0],red[1]), fmaxf(red[2],red[3]));
    float e = __expf(v - m);
    float s = e;
    #pragma unroll
    for (int d=32; d>=1; d>>=1) s += __shfl_xor(s, d);
    if ((tid & 63) == 0) red[4 + (tid>>6)] = s;
    __syncthreads();
    s = red[4]+red[5]+red[6]+red[7];
    pcb[(size_t)b*65536 + (size_t)c*256 + tid] = f2b(e / s);
}

// ======================================================================
// yc via MFMA: y_c[n][d] = sum_o V[n][o]*pc[o][d], bf16 in/out.
// ======================================================================
__global__ __launch_bounds__(256) void yc_mfma_kernel(
    const u16* __restrict__ VT, const u16* __restrict__ pcb, u16* __restrict__ ycb)
{
    __shared__ __align__(16) u16 Vl[64*32];    // [64 n][32 o], slot = (o>>3)^(n&3)
    __shared__ __align__(16) u16 Pcl[64*32];   // [64 d][32 o], slot = (o>>3)^(d&3)
    const int tid = threadIdx.x;
    const int w = tid >> 6, lane = tid & 63;
    const int q4 = lane >> 4, l = lane & 15;
    const int n0 = blockIdx.x * 64, d0 = blockIdx.y * 64, b = blockIdx.z;

    f32x4 acc[4];
    #pragma unroll
    for (int dt=0; dt<4; dt++) acc[dt] = (f32x4){0.f,0.f,0.f,0.f};

    const int so = tid >> 3;       // o-row 0..31
    const int sj = tid & 7;        // 8-col group

    for (int oc=0; oc<8; oc++){
        const int o0 = oc*32;
        __syncthreads();
        {
            uint4 v = *(const uint4*)(VT + ((size_t)(b*IC + o0 + so))*NPOS + n0 + sj*8);
            u16 tv[8]; *(uint4*)tv = v;
            #pragma unroll
            for (int m=0;m<8;m++){
                int n = sj*8 + m;
                Vl[n*32 + ((((so>>3) ^ (n&3)))<<3) + (so&7)] = tv[m];
            }
            uint4 pv = *(const uint4*)(pcb + (size_t)b*65536 + (size_t)(o0 + so)*256 + d0 + sj*8);
            u16 tp[8]; *(uint4*)tp = pv;
            #pragma unroll
            for (int m=0;m<8;m++){
                int d = sj*8 + m;
                Pcl[d*32 + ((((so>>3) ^ (d&3)))<<3) + (so&7)] = tp[m];
            }
        }
        __syncthreads();
        bf16x8 af = *(const bf16x8*)&Vl[(w*16 + l)*32 + ((q4 ^ (l&3))<<3)];
        #pragma unroll
        for (int dt=0; dt<4; dt++){
            bf16x8 bfr = *(const bf16x8*)&Pcl[(dt*16 + l)*32 + ((q4 ^ (l&3))<<3)];
            acc[dt] = __builtin_amdgcn_mfma_f32_16x16x32_bf16(af, bfr, acc[dt], 0, 0, 0);
        }
    }

    // C: row n = w*16 + q4*4 + reg, col d = d0 + dt*16 + l
    #pragma unroll
    for (int dt=0; dt<4; dt++)
        #pragma unroll
        for (int reg=0; reg<4; reg++)
            ycb[((size_t)(b*NPOS + n0 + w*16 + q4*4 + reg))*IC + d0 + dt*16 + l] = f2b(acc[dt][reg]);
}

// ======================================================================
// MFMA flash attention (R5/R8-proven): Bq=64/Bk=64, counted vmcnt(8)
// pipeline, XCD batch pinning, nontemporal Q/O. LDS 74.75 KB.
// sshift=1: 512 blocks (2/CU exact), 32 tiles each; half the partial I/O.
// ======================================================================
__global__ __launch_bounds__(256) void flash_mfma_kernel(
    const u16* __restrict__ Q, const u16* __restrict__ K, const u16* __restrict__ VT,
    u16* __restrict__ opart0, u16* __restrict__ opartx, float* __restrict__ lpart,
    int sshift)
{
    __shared__ __align__(16) u32 Kt[8192];   // 32 KB: K tile (swizzled); epilogue O zones
    __shared__ __align__(16) u32 Vt[8192];   // 32 KB: V^T tile (swizzled)
    __shared__ __align__(16) u16 Pl[4608];   // 9.25 KB: wave-private P, stride 72
    const int tid  = threadIdx.x;
    const int w    = tid >> 6;
    const int lane = tid & 63;
    const int q4   = lane >> 4;
    const int l    = lane & 15;
    const int S    = 1 << sshift;

    const int id   = blockIdx.x;
    const int xcd  = id & 7;
    const int b    = xcd >> 1;                 // NB==4
    const int h    = xcd & 1;
    const int r    = id >> 3;                  // [0, 32*S)
    const int n0   = ((r & 31) | (h << 5)) * 64;
    const int seg  = r >> 5;                   // [0, S)
    const int tiles = 64 >> sshift;
    const int kt0   = seg * tiles;

    bf16x8 qf[8];
    {
        const u16* qrow = Q + ((size_t)(b*NPOS + n0 + w*16 + l))*IC;
        #pragma unroll
        for (int f=0; f<8; f++){
            u32x4 qv = __builtin_nontemporal_load((const u32x4*)(qrow + f*32 + q4*8));
            qf[f] = *(bf16x8*)&qv;
        }
    }

    f32x4 oacc[16];
    #pragma unroll
    for (int t=0;t<16;t++) oacc[t] = (f32x4){0.f,0.f,0.f,0.f};
    float lrow[4] = {0.f, 0.f, 0.f, 0.f};

    u16* Pz = Pl + w*1152;   // wave-private P zone: rows m*72, m=0..15

    auto stage_k = [&](int m0s){
        #pragma unroll
        for (int j=0;j<8;j++){
            int call = w*8 + j;
            int rr = call*2 + (lane>>5);
            int c = (lane & 31) ^ (rr & 7);
            const u16* g = K + ((size_t)(b*NPOS + m0s + rr))*IC + c*8;
            __builtin_amdgcn_global_load_lds(
                (const __attribute__((address_space(1))) u32*)(const void*)g,
                (__attribute__((address_space(3))) u32*)(void*)&Kt[call*256], 16, 0, 0);
        }
    };
    auto stage_v = [&](int m0s){
        #pragma unroll
        for (int j=0;j<8;j++){
            int call = w*8 + j;
            int d = call*8 + (lane>>3);
            int c = (lane & 7) ^ (d & 7);
            const u16* g = VT + ((size_t)(b*IC + d))*NPOS + m0s + c*8;
            __builtin_amdgcn_global_load_lds(
                (const __attribute__((address_space(1))) u32*)(const void*)g,
                (__attribute__((address_space(3))) u32*)(void*)&Vt[call*256], 16, 0, 0);
        }
    };

    stage_k(kt0*64);
    stage_v(kt0*64);
    asm volatile("s_waitcnt vmcnt(0)" ::: "memory");
    __builtin_amdgcn_sched_barrier(0);
    __builtin_amdgcn_s_barrier();
    __builtin_amdgcn_sched_barrier(0);

    for (int kti=0; kti<tiles; kti++){
        const bool more = (kti + 1 < tiles);
        const int mn = (kt0 + kti + 1)*64;

        f32x4 sac[4];
        #pragma unroll
        for (int t=0;t<4;t++) sac[t] = (f32x4){0.f,0.f,0.f,0.f};
        __builtin_amdgcn_s_setprio(1);
        #pragma unroll
        for (int f=0; f<8; f++){
            #pragma unroll
            for (int t=0;t<4;t++){
                int rr = t*16 + l;
                int c = (f*4 + q4) ^ (rr & 7);
                bf16x8 kf = *(const bf16x8*)((const u16*)Kt + rr*256 + c*8);
                sac[t] = __builtin_amdgcn_mfma_f32_16x16x32_bf16(qf[f], kf, sac[t], 0, 0, 0);
            }
        }
        __builtin_amdgcn_s_setprio(0);

        __builtin_amdgcn_sched_barrier(0);
        __builtin_amdgcn_s_barrier();            // A: all waves done reading Kt
        __builtin_amdgcn_sched_barrier(0);

        if (more) stage_k(mn);

        #pragma unroll
        for (int reg=0; reg<4; reg++){
            float p0 = __expf(sac[0][reg]), p1 = __expf(sac[1][reg]);
            float p2 = __expf(sac[2][reg]), p3 = __expf(sac[3][reg]);
            lrow[reg] += (p0+p1) + (p2+p3);
            int m = q4*4 + reg;
            Pz[m*72 + l]      = f2b(p0);
            Pz[m*72 + 16 + l] = f2b(p1);
            Pz[m*72 + 32 + l] = f2b(p2);
            Pz[m*72 + 48 + l] = f2b(p3);
        }

        if (more) { asm volatile("s_waitcnt vmcnt(8)" ::: "memory"); }
        else      { asm volatile("s_waitcnt vmcnt(0)" ::: "memory"); }
        __builtin_amdgcn_sched_barrier(0);
        __builtin_amdgcn_s_barrier();            // B: V(t) visible to all waves
        __builtin_amdgcn_sched_barrier(0);

        __builtin_amdgcn_s_setprio(1);
        #pragma unroll
        for (int s2=0; s2<2; s2++){
            bf16x8 pa = *(const bf16x8*)(Pz + l*72 + s2*32 + q4*8);
            #pragma unroll
            for (int t=0;t<16;t++){
                int d = t*16 + l;
                int c = (s2*4 + q4) ^ (d & 7);
                bf16x8 vb = *(const bf16x8*)((const u16*)Vt + d*64 + c*8);
                oacc[t] = __builtin_amdgcn_mfma_f32_16x16x32_bf16(pa, vb, oacc[t], 0, 0, 0);
            }
        }
        __builtin_amdgcn_s_setprio(0);

        __builtin_amdgcn_sched_barrier(0);
        __builtin_amdgcn_s_barrier();            // C: all waves done reading Vt
        __builtin_amdgcn_sched_barrier(0);

        if (more) {
            stage_v(mn);
            asm volatile("s_waitcnt vmcnt(8)" ::: "memory");
        } else {
            asm volatile("s_waitcnt vmcnt(0)" ::: "memory");
        }
        __builtin_amdgcn_sched_barrier(0);
        __builtin_amdgcn_s_barrier();            // D: K(t+1) visible to all waves
        __builtin_amdgcn_sched_barrier(0);
    }

    #pragma unroll
    for (int reg=0; reg<4; reg++){
        float v = lrow[reg];
        v += __shfl_xor(v, 1); v += __shfl_xor(v, 2);
        v += __shfl_xor(v, 4); v += __shfl_xor(v, 8);
        if (l == 0)
            lpart[((size_t)(seg*NB + b))*NPOS + n0 + w*16 + q4*4 + reg] = v;
    }

    __syncthreads();
    u16* Ez = (u16*)Kt + w*4096;   // 8 KB per wave
    #pragma unroll
    for (int t=0;t<16;t++)
        #pragma unroll
        for (int reg=0;reg<4;reg++)
            Ez[(t*16 + l)*16 + q4*4 + reg] = f2b(oacc[t][reg]);
    u16* base = (seg == 0) ? opart0 : (opartx + (size_t)(seg-1)*((size_t)NB*IC*NPOS));
    u16* dst = base + (size_t)b*(IC*NPOS) + n0 + w*16;
    for (int p=0; p<32; p++){
        int d = p*8 + (lane>>3);
        u32 val = *(const u32*)(Ez + d*16 + (lane&7)*2);
        __builtin_nontemporal_store(val, (u32*)(dst + (size_t)d*NPOS + (lane&7)*2));
    }
}

// ======================================================================
// z = x + gs*(Ws@y_s + Ws_b) + gc*(Wc@y_c + Wc_b)   (fp32 out to d_out)
// LDS-staged fused combine (R8-proven).
// ======================================================================
__global__ __launch_bounds__(256) void z_kernel(
    const float* __restrict__ x,
    const u16* __restrict__ opart0, const u16* __restrict__ opartx,
    const float* __restrict__ lpart, int S,
    const u16* __restrict__ ycb,
    const float* __restrict__ wswT, const float* __restrict__ wcwT,
    const float* __restrict__ wsb, const float* __restrict__ wcb,
    const float* __restrict__ gs, const float* __restrict__ gc,
    float* __restrict__ zout)
{
    __shared__ __align__(16) float Wsl[64*32];
    __shared__ __align__(16) float Wcl[64*32];
    __shared__ __align__(16) float rlL[256];
    __shared__ __align__(16) u16 ysl[32*264];   // [32 i][256 p] stride 264
    __shared__ __align__(16) u16 ycl[32*264];
    const int tid = threadIdx.x;
    const int p = blockIdx.x * 256 + tid;
    const int cbase = blockIdx.y * 32;
    const int b = blockIdx.z;
    {
        int i = tid >> 2, c8 = (tid & 3) * 8;
        const float* s1 = wswT + i*64 + cbase + c8;
        const float* s2 = wcwT + i*64 + cbase + c8;
        *(float4*)&Wsl[i*32 + c8]     = *(const float4*)s1;
        *(float4*)&Wsl[i*32 + c8 + 4] = *(const float4*)(s1+4);
        *(float4*)&Wcl[i*32 + c8]     = *(const float4*)s2;
        *(float4*)&Wcl[i*32 + c8 + 4] = *(const float4*)(s2+4);
    }
    // softmax denominator: depends only on n = p & 4095
    {
        float Ls = 0.f;
        for (int s=0; s<S; s++)
            Ls += lpart[((size_t)(s*NB + b))*NPOS + (p & 4095)];
        rlL[tid] = 1.f / Ls;
    }

    float as[32], ac[32];
    #pragma unroll
    for (int c=0;c<32;c++){ as[c]=0.f; ac[c]=0.f; }

    const size_t CHUNK = (size_t)NB*IC*NPOS;
    const size_t bbase = (size_t)b*(IC*NPOS) + (size_t)blockIdx.x*256;

    for (int half=0; half<2; half++){
        __syncthreads();   // W/rlL ready (first iter); prior LDS reads done (second)
        #pragma unroll
        for (int k=0;k<4;k++){
            int ci  = tid + k*256;         // 0..1023
            int il  = ci >> 5;             // 0..31
            int i   = half*32 + il;        // z-channel 0..63
            int oct = ci & 31;             // 8-p group
            size_t gidx = bbase + (size_t)i*HW + oct*8;
            float y8[8] = {0,0,0,0,0,0,0,0};
            for (int s=0;s<S;s++){
                const u16* psrc = (s==0) ? opart0 : (opartx + (size_t)(s-1)*CHUNK);
                uint4 v = *(const uint4*)(psrc + gidx);
                y8[0]+=blo(v.x); y8[1]+=bhi(v.x); y8[2]+=blo(v.y); y8[3]+=bhi(v.y);
                y8[4]+=blo(v.z); y8[5]+=bhi(v.z); y8[6]+=blo(v.w); y8[7]+=bhi(v.w);
            }
            u32 pk[4];
            #pragma unroll
            for (int j=0;j<4;j++){
                float a0 = y8[2*j]   * rlL[oct*8 + 2*j];
                float a1 = y8[2*j+1] * rlL[oct*8 + 2*j+1];
                pk[j] = (u32)f2b(a0) | ((u32)f2b(a1) << 16);
            }
            *(uint4*)&ysl[il*264 + oct*8] = *(uint4*)pk;
            uint4 vc = *(const uint4*)(ycb + gidx);
            *(uint4*)&ycl[il*264 + oct*8] = vc;
        }
        __syncthreads();
        for (int il=0; il<32; il++){
            int i = half*32 + il;
            float ysv = b2f(ysl[il*264 + tid]);
            float ycv = b2f(ycl[il*264 + tid]);
            #pragma unroll
            for (int c=0;c<32;c++){
                as[c] = fmaf(Wsl[i*32+c], ysv, as[c]);
                ac[c] = fmaf(Wcl[i*32+c], ycv, ac[c]);
            }
        }
    }

    float gsv = gs[0], gcv = gc[0];
    #pragma unroll
    for (int c=0;c<32;c++){
        int cg = cbase + c;
        float xv = x[((size_t)b*CH + cg)*HW + p];
        float zv = fmaf(gsv, as[c] + wsb[cg], xv);
        zv = fmaf(gcv, ac[c] + wcb[cg], zv);
        zout[((size_t)b*CH + cg)*HW + p] = zv;
    }
}

// ======================================================================
// conv3x3 (64->16) + ReLU. 128 px x 2 o-halves per 256-thr block.
// ======================================================================
__global__ __launch_bounds__(256) void conv1_kernel(
    const float* __restrict__ z, const float* __restrict__ m1wT, const float* __restrict__ m1b,
    float* __restrict__ hmid)
{
    const int tid = threadIdx.x;
    const int p = blockIdx.x * 128 + (tid & 127);
    const int oh = (tid >> 7) * 8;
    const int b = blockIdx.y;
    const int y = p >> 7, xx = p & 127;
    float acc[8];
    #pragma unroll
    for (int o=0;o<8;o++) acc[o]=0.f;
    for (int c=0;c<64;c++){
        const float* zp = z + ((size_t)b*CH + c)*HW;
        #pragma unroll
        for (int t=0;t<9;t++){
            int dy = t/3 - 1, dx = t%3 - 1;
            int yy = y + dy, xv = xx + dx;
            float zv = 0.f;
            if (yy >= 0 && yy < 128 && xv >= 0 && xv < 128) zv = zp[yy*128 + xv];
            const float* w = m1wT + (c*9 + t)*16 + oh;
            #pragma unroll
            for (int o=0;o<8;o++) acc[o] = fmaf(w[o], zv, acc[o]);
        }
    }
    #pragma unroll
    for (int o=0;o<8;o++)
        hmid[((size_t)b*16 + oh + o)*HW + p] = fmaxf(acc[o] + m1b[oh + o], 0.f);
}

// ======================================================================
// conv3x3 (16->1), logit out (fp32)
// ======================================================================
__global__ __launch_bounds__(256) void conv2_kernel(
    const float* __restrict__ hmid, const float* __restrict__ m2w, const float* __restrict__ m2b,
    float* __restrict__ logit)
{
    const int idx = blockIdx.x * 256 + threadIdx.x;
    const int b = idx >> 14, p = idx & 16383;
    const int y = p >> 7, xx = p & 127;
    float acc = 0.f;
    for (int c=0;c<16;c++){
        const float* hp = hmid + ((size_t)b*16 + c)*HW;
        #pragma unroll
        for (int t=0;t<9;t++){
            int dy = t/3 - 1, dx = t%3 - 1;
            int yy = y + dy, xv = xx + dx;
            if (yy >= 0 && yy < 128 && xv >= 0 && xv < 128)
                acc = fmaf(m2w[c*9+t], hp[yy*128 + xv], acc);
        }
    }
    logit[idx] = acc + m2b[0];
}

// ======================================================================
extern "C" void kernel_launch(void* const* d_in, const int* in_sizes, int n_in,
                              void* d_out, int out_size, void* d_ws, size_t ws_size,
                              hipStream_t stream)
{
    const float* x    = (const float*)d_in[0];
    const float* g_w  = (const float*)d_in[1];
    const float* g_b  = (const float*)d_in[2];
    const float* th_w = (const float*)d_in[3];
    const float* th_b = (const float*)d_in[4];
    const float* ph_w = (const float*)d_in[5];
    const float* ph_b = (const float*)d_in[6];
    const float* ws_w = (const float*)d_in[7];
    const float* ws_b = (const float*)d_in[8];
    const float* wc_w = (const float*)d_in[9];
    const float* wc_b = (const float*)d_in[10];
    const float* gs   = (const float*)d_in[11];
    const float* gc   = (const float*)d_in[12];
    const float* m1w  = (const float*)d_in[13];
    const float* m1b  = (const float*)d_in[14];
    const float* m2w  = (const float*)d_in[15];
    const float* m2b  = (const float*)d_in[16];

    char* ws = (char*)d_ws;
    u16*   Qb   = (u16*)  (ws + 0);
    u16*   Kb   = (u16*)  (ws + 8388608);
    u16*   VTb  = (u16*)  (ws + 16777216);
    u16*   ysT  = (u16*)  (ws + 25165824);   // opart0
    u16*   ycb  = (u16*)  (ws + 33554432);
    u16*   wbf  = (u16*)  (ws + 41943040);
    u16*   pcb  = (u16*)  (ws + 42991616);   // 512 KB bf16 softmax weights
    float* fcp4 = (float*)(ws + 44040192);   // legacy 4-seg partials (sshift==0)
    float* hmid = (float*)(ws + 44040192);
    float* lpart= (float*)(ws + 44040192);   // used during flash window + z only
    float* wswT = (float*)(ws + 48234496);
    float* wcwT = (float*)(ws + 48250880);
    float* m1wT = (float*)(ws + 48267264);
    u16*   opartx = (u16*)(ws + 48304128);   // (S-1) x 8MB segments (flash window)

    float* logit = (float*)d_out;
    float* zout  = (float*)d_out + 65536;

    // split-K factor: S=2 fills all 256 CUs at the 2-block LDS limit;
    // larger S only multiplies partial-O traffic.
    int sshift = 0;
    if (ws_size >= 48304128ULL + 1ULL*8388608ULL) sshift = 1;

    // fc split-n config: 8 segs in the (pre-flash-dead) opartx region when
    // available; legacy 4 segs in the 4MB region otherwise.
    int nslg = (sshift >= 1) ? 3 : 2;
    float* fcp = (sshift >= 1) ? (float*)(ws + 48304128) : fcp4;

    prep_kernel<<<256, 256, 0, stream>>>(ws_w, wc_w, m1w, th_w, ph_w, g_w,
                                         wswT, wcwT, m1wT, wbf);
    qkv_mfma_kernel<<<dim3(64,4), 256, 0, stream>>>(x, wbf, th_b, ph_b, g_b, Qb, Kb, VTb);
    fc_mfma_kernel<<<dim3(4,4,NB << nslg), 256, 0, stream>>>(Qb, Kb, fcp, nslg);
    softmax_fc_kernel<<<1024, 256, 0, stream>>>(fcp, pcb, 1 << nslg);
    yc_mfma_kernel<<<dim3(64,4,4), 256, 0, stream>>>(VTb, pcb, ycb);
    flash_mfma_kernel<<<dim3(NB * 64 * (1 << sshift)), 256, 0, stream>>>(Qb, Kb, VTb, ysT, opartx, lpart, sshift);
    z_kernel<<<dim3(64,2,4), 256, 0, stream>>>(x, ysT, opartx, lpart, 1 << sshift, ycb,
                                               wswT, wcwT, ws_b, wc_b, gs, gc, zout);
    conv1_kernel<<<dim3(128,4), 256, 0, stream>>>(zout, m1wT, m1b, hmid);
    conv2_kernel<<<256, 256, 0, stream>>>(hmid, m2w, m2b, logit);
}